// Round 10
// baseline (431.605 us; speedup 1.0000x reference)
//
#include <hip/hip_runtime.h>
#include <hip/hip_bf16.h>
#include <hip/hip_cooperative_groups.h>

namespace cg = cooperative_groups;

#define NTOK 4096   // 64*64 tokens per batch
#define NPOOL 1024  // 32*32 pooled tokens per batch

using short8 = __attribute__((ext_vector_type(8))) short;
using f32x4  = __attribute__((ext_vector_type(4))) float;

__device__ __forceinline__ unsigned short f2bf(float f) {
  __hip_bfloat16 h = __float2bfloat16(f);
  return __builtin_bit_cast(unsigned short, h);
}

// Map local tile row m (0..63) to a global x row such that rows 4*p..4*p+3 are
// the 2x2 pooling corners of pooled row bx*16+p.
__device__ __forceinline__ int pool_row(int bx, int m) {
  int pg = bx * 16 + (m >> 2);
  int corner = m & 3;
  int batch = pg >> 10;
  int pl = pg & 1023;
  int pi = pl >> 5, pj = pl & 31;
  return (batch << 12) + ((2 * pi + (corner >> 1)) << 6) + 2 * pj + (corner & 1);
}

// ONE cooperative kernel, 256 blocks x 512 threads (1 block/CU, co-resident).
// Phase 1: pack weights (+ pre-stage fgh tile-0 x, which needs no wcatT).
// Phase 2: fgh projection, 2 sequential 64-row tiles (R7-verified body).
// Phase 3: flash attention + fused out-GEMM + residual (R9-verified body).
// grid.sync() replaces 3 kernel-launch gaps (~12-17 us each).
__global__ __launch_bounds__(512) void fused_all(
    const float* __restrict__ x,
    const float* __restrict__ wf,
    const float* __restrict__ wg,
    const float* __restrict__ wh,
    const float* __restrict__ wo,
    const float* __restrict__ gamma,
    float* __restrict__ Out,
    unsigned short* __restrict__ gB,
    unsigned short* __restrict__ fB,
    unsigned short* __restrict__ hT,
    unsigned short* __restrict__ wcatT,
    unsigned short* __restrict__ woT) {
  // phase 2: As[64][520] @0 (66560 B)
  // phase 3: fS[64][72] @0 ; hS[256][72] @4608 ; pS[128][72] @23040 ; oS[128][264] @0
  __shared__ unsigned short lds[33792];  // 67584 B

  const int tid = threadIdx.x;
  const int wave = tid >> 6, lane = tid & 63;
  const int col = lane & 15, rgrp = lane >> 4;

  // ---------------- phase 1: pack weights (grid-stride) ----------------
  for (int i = blockIdx.x * 512 + tid; i < 384 * 512 + 512 * 256; i += 256 * 512) {
    if (i < 384 * 512) {
      int n = i >> 9, k = i & 511;
      float v = (n < 64) ? wf[k * 64 + n]
              : (n < 128) ? wg[k * 64 + (n - 64)]
                          : wh[k * 256 + (n - 128)];
      wcatT[i] = f2bf(v);
    } else {
      int j = i - 384 * 512;
      int n = j >> 8, k = j & 255;
      woT[j] = f2bf(wo[(size_t)k * 512 + n]);
    }
  }

  // pre-stage fgh tile-0 x (independent of wcatT; overlaps pack tail)
  {
    const int bx = blockIdx.x * 2;
    const int xm = tid >> 3, xk4 = (tid & 7) << 2;
    const float* xrow = x + (size_t)pool_row(bx, xm) * 512 + xk4;
    unsigned short* dst = &lds[xm * 520 + xk4];
#pragma unroll
    for (int kt = 0; kt < 16; ++kt) {
      float4 v = *(const float4*)(xrow + kt * 32);
      ushort4 o4;
      o4.x = f2bf(v.x); o4.y = f2bf(v.y); o4.z = f2bf(v.z); o4.w = f2bf(v.w);
      *(ushort4*)(dst + kt * 32) = o4;
    }
  }

  __threadfence();          // device-scope visibility of wcatT/woT across XCDs
  cg::this_grid().sync();

  // ---------------- phase 2: fgh projection, 2 tiles ----------------
  for (int t = 0; t < 2; ++t) {
    const int bx = blockIdx.x * 2 + t;
    if (t == 1) {
      __syncthreads();  // tile-0 epilogue LDS reads done
      const int xm = tid >> 3, xk4 = (tid & 7) << 2;
      const float* xrow = x + (size_t)pool_row(bx, xm) * 512 + xk4;
      unsigned short* dst = &lds[xm * 520 + xk4];
#pragma unroll
      for (int kt = 0; kt < 16; ++kt) {
        float4 v = *(const float4*)(xrow + kt * 32);
        ushort4 o4;
        o4.x = f2bf(v.x); o4.y = f2bf(v.y); o4.z = f2bf(v.z); o4.w = f2bf(v.w);
        *(ushort4*)(dst + kt * 32) = o4;
      }
      __syncthreads();  // staging visible
    }
    const int wcol = wave * 48;

    f32x4 acc[4][3];
#pragma unroll
    for (int mt = 0; mt < 4; ++mt)
#pragma unroll
      for (int nt = 0; nt < 3; ++nt) acc[mt][nt] = (f32x4){0.f, 0.f, 0.f, 0.f};

    for (int kt = 0; kt < 16; ++kt) {
      short8 am[4];
#pragma unroll
      for (int mt = 0; mt < 4; ++mt)
        am[mt] = *(const short8*)&lds[(mt * 16 + col) * 520 + kt * 32 + rgrp * 8];
#pragma unroll
      for (int nt = 0; nt < 3; ++nt) {
        short8 bn = *(const short8*)(wcatT + (size_t)(wcol + nt * 16 + col) * 512 + kt * 32 + rgrp * 8);
#pragma unroll
        for (int mt = 0; mt < 4; ++mt)
          acc[mt][nt] = __builtin_amdgcn_mfma_f32_16x16x32_bf16(am[mt], bn, acc[mt][nt], 0, 0, 0);
      }
    }
    __syncthreads();

    // epilogue assembly in LDS (alias over staging)
    unsigned short* gO = lds;          // [64][72]
    unsigned short* fO = lds + 4608;   // [16][72]
    unsigned short* hO = lds + 5760;   // [256][24]
#pragma unroll
    for (int mt = 0; mt < 4; ++mt) {
#pragma unroll
      for (int nt = 0; nt < 3; ++nt) {
        int n = wcol + nt * 16 + col;
        f32x4 a = acc[mt][nt];
        if (n < 64) {
          float mx = fmaxf(fmaxf(a[0], a[1]), fmaxf(a[2], a[3]));
          fO[(mt * 4 + rgrp) * 72 + n] = f2bf(mx);
        } else if (n < 128) {
#pragma unroll
          for (int reg = 0; reg < 4; ++reg)
            gO[(mt * 16 + rgrp * 4 + reg) * 72 + (n - 64)] = f2bf(a[reg]);
        } else {
          float mx = fmaxf(fmaxf(a[0], a[1]), fmaxf(a[2], a[3]));
          hO[(n - 128) * 24 + (mt * 4 + rgrp)] = f2bf(mx);
        }
      }
    }
    __syncthreads();

    const int b = bx >> 6, pkb = (bx & 63) * 16;
    {
      int m = tid >> 3, d8 = (tid & 7) << 3;
      *(uint4*)(gB + (size_t)pool_row(bx, m) * 64 + d8) = *(const uint4*)&gO[m * 72 + d8];
    }
    if (tid < 128) {
      int pr = tid >> 3, d8 = (tid & 7) << 3;
      *(uint4*)(fB + (size_t)(bx * 16 + pr) * 64 + d8) = *(const uint4*)&fO[pr * 72 + d8];
    }
    {
      int dv = tid >> 1, p8 = (tid & 1) << 3;
      *(uint4*)(hT + (((size_t)b * 256 + dv) << 10) + pkb + p8) = *(const uint4*)&hO[dv * 24 + p8];
    }
  }

  __threadfence();          // g/f/h visible across XCDs
  cg::this_grid().sync();

  // ---------------- phase 3: attention + fused out-GEMM ----------------
  {
    const int b = blockIdx.x >> 5, qt = blockIdx.x & 31;
    const unsigned short* Gb = gB + ((size_t)b * NTOK + qt * 128) * 64;
    const unsigned short* Fb = fB + (size_t)b * NPOOL * 64;
    const unsigned short* Hb = hT + (size_t)b * 256 * NPOOL;

    short8 ag[2];
#pragma unroll
    for (int ks = 0; ks < 2; ++ks)
      ag[ks] = *(const short8*)(Gb + (size_t)(wave * 16 + col) * 64 + ks * 32 + rgrp * 8);

    f32x4 oacc[16];
#pragma unroll
    for (int t = 0; t < 16; ++t) oacc[t] = (f32x4){0.f, 0.f, 0.f, 0.f};
    float m_run[4], l_run[4];
#pragma unroll
    for (int r = 0; r < 4; ++r) { m_run[r] = -1e30f; l_run[r] = 0.f; }

    const int fk = tid >> 3, fd8 = (tid & 7) << 3;

    for (int kc = 0; kc < 16; ++kc) {
      __syncthreads();
      *(uint4*)&lds[fk * 72 + fd8] =
          *(const uint4*)(Fb + (size_t)(kc * 64 + fk) * 64 + fd8);
#pragma unroll
      for (int r = 0; r < 4; ++r) {
        int j = tid + r * 512;
        int dv = j >> 3, k8 = (j & 7) << 3;
        *(uint4*)&lds[4608 + dv * 72 + k8] =
            *(const uint4*)(Hb + (size_t)dv * NPOOL + kc * 64 + k8);
      }
      __syncthreads();

      // QK^T
      f32x4 s[4];
#pragma unroll
      for (int t = 0; t < 4; ++t) s[t] = (f32x4){0.f, 0.f, 0.f, 0.f};
#pragma unroll
      for (int ks = 0; ks < 2; ++ks) {
#pragma unroll
        for (int t = 0; t < 4; ++t) {
          short8 bf = *(const short8*)&lds[(t * 16 + col) * 72 + ks * 32 + rgrp * 8];
          s[t] = __builtin_amdgcn_mfma_f32_16x16x32_bf16(ag[ks], bf, s[t], 0, 0, 0);
        }
      }

      // online softmax with exact defer-rescale
      float cm[4];
#pragma unroll
      for (int r = 0; r < 4; ++r) {
        cm[r] = fmaxf(fmaxf(s[0][r], s[1][r]), fmaxf(s[2][r], s[3][r]));
#pragma unroll
        for (int msk = 1; msk < 16; msk <<= 1) cm[r] = fmaxf(cm[r], __shfl_xor(cm[r], msk));
      }
      bool upd = false;
#pragma unroll
      for (int r = 0; r < 4; ++r) upd |= (cm[r] > m_run[r]);
      if (__any(upd)) {
        float alpha[4];
#pragma unroll
        for (int r = 0; r < 4; ++r) {
          float mn = fmaxf(m_run[r], cm[r]);
          alpha[r] = __expf(m_run[r] - mn);
          m_run[r] = mn;
          l_run[r] *= alpha[r];
        }
#pragma unroll
        for (int t = 0; t < 16; ++t) {
#pragma unroll
          for (int r = 0; r < 4; ++r) oacc[t][r] *= alpha[r];
        }
      }

      float rs[4] = {0.f, 0.f, 0.f, 0.f};
      const int prow = wave * 16 + rgrp * 4;
#pragma unroll
      for (int t = 0; t < 4; ++t) {
#pragma unroll
        for (int r = 0; r < 4; ++r) {
          float p = __expf(s[t][r] - m_run[r]);
          rs[r] += p;
          lds[23040 + (prow + r) * 72 + t * 16 + col] = f2bf(p);
        }
      }
#pragma unroll
      for (int r = 0; r < 4; ++r) {
#pragma unroll
        for (int msk = 1; msk < 16; msk <<= 1) rs[r] += __shfl_xor(rs[r], msk);
        l_run[r] += rs[r];
      }

      // PV (pS is wave-private)
      short8 ap[2];
#pragma unroll
      for (int ks = 0; ks < 2; ++ks)
        ap[ks] = *(const short8*)&lds[23040 + (wave * 16 + col) * 72 + ks * 32 + rgrp * 8];
#pragma unroll
      for (int t = 0; t < 16; ++t) {
#pragma unroll
        for (int ks = 0; ks < 2; ++ks) {
          short8 bh = *(const short8*)&lds[4608 + (t * 16 + col) * 72 + ks * 32 + rgrp * 8];
          oacc[t] = __builtin_amdgcn_mfma_f32_16x16x32_bf16(ap[ks], bh, oacc[t], 0, 0, 0);
        }
      }
    }

    // epilogue 1: normalize, assemble bf16 o in LDS (oS[128][264] @0)
    float inv[4];
#pragma unroll
    for (int r = 0; r < 4; ++r) inv[r] = 1.0f / l_run[r];
    __syncthreads();
    const int qrow = wave * 16 + rgrp * 4;
#pragma unroll
    for (int t = 0; t < 16; ++t) {
#pragma unroll
      for (int r = 0; r < 4; ++r)
        lds[(qrow + r) * 264 + t * 16 + col] = f2bf(oacc[t][r] * inv[r]);
    }
    __syncthreads();

    // epilogue 2: fused out-GEMM + residual (standalone-gemm wave shape)
    const float gm = gamma[0];
    const int wr = (wave >> 2) * 64;
    const int wc = (wave & 3) * 64;
    const size_t rowbase = (size_t)b * NTOK + (size_t)qt * 128 + wr;
#pragma unroll
    for (int c = 0; c < 2; ++c) {
      f32x4 acc2[4][4];
#pragma unroll
      for (int mt = 0; mt < 4; ++mt)
#pragma unroll
        for (int nt = 0; nt < 4; ++nt) acc2[mt][nt] = (f32x4){0.f, 0.f, 0.f, 0.f};
#pragma unroll
      for (int kt = 0; kt < 8; ++kt) {
        short8 am[4];
#pragma unroll
        for (int mt = 0; mt < 4; ++mt)
          am[mt] = *(const short8*)&lds[(wr + mt * 16 + col) * 264 + kt * 32 + rgrp * 8];
#pragma unroll
        for (int nt = 0; nt < 4; ++nt) {
          short8 bn = *(const short8*)(woT + (size_t)(c * 256 + wc + nt * 16 + col) * 256 + kt * 32 + rgrp * 8);
#pragma unroll
          for (int mt = 0; mt < 4; ++mt)
            acc2[mt][nt] = __builtin_amdgcn_mfma_f32_16x16x32_bf16(am[mt], bn, acc2[mt][nt], 0, 0, 0);
        }
      }
#pragma unroll
      for (int mt = 0; mt < 4; ++mt) {
#pragma unroll
        for (int nt = 0; nt < 4; ++nt) {
          int n = c * 256 + wc + nt * 16 + col;
#pragma unroll
          for (int reg = 0; reg < 4; ++reg) {
            size_t off = (rowbase + mt * 16 + rgrp * 4 + reg) * 512 + n;
            Out[off] = gm * acc2[mt][nt][reg] + x[off];
          }
        }
      }
    }
  }
}

extern "C" void kernel_launch(void* const* d_in, const int* in_sizes, int n_in,
                              void* d_out, int out_size, void* d_ws, size_t ws_size,
                              hipStream_t stream) {
  (void)in_sizes; (void)n_in; (void)out_size; (void)ws_size;
  const float* x     = (const float*)d_in[0];
  const float* wf    = (const float*)d_in[1];
  const float* wg    = (const float*)d_in[2];
  const float* wh    = (const float*)d_in[3];
  const float* wo    = (const float*)d_in[4];
  const float* gamma = (const float*)d_in[5];
  float* out = (float*)d_out;

  unsigned short* ws = (unsigned short*)d_ws;
  unsigned short* gB    = ws + 8388608;     // [32768][64]
  unsigned short* fB    = ws + 10485760;    // [8192][64]
  unsigned short* hT    = ws + 11010048;    // [8][256][1024]
  unsigned short* wcatT = ws + 13107200;    // [384][512]
  unsigned short* woT   = ws + 13303808;    // [512][256]

  void* args[] = {(void*)&x, (void*)&wf, (void*)&wg, (void*)&wh, (void*)&wo,
                  (void*)&gamma, (void*)&out, (void*)&gB, (void*)&fB, (void*)&hT,
                  (void*)&wcatT, (void*)&woT};
  hipLaunchCooperativeKernel((const void*)fused_all, dim3(256), dim3(512),
                             args, 0, stream);
}

// Round 11
// 360.598 us; speedup vs baseline: 1.1969x; 1.1969x over previous
//
#include <hip/hip_runtime.h>
#include <hip/hip_bf16.h>

#define NTOK 4096   // 64*64 tokens per batch
#define NPOOL 1024  // 32*32 pooled tokens per batch

using short8 = __attribute__((ext_vector_type(8))) short;
using f32x4  = __attribute__((ext_vector_type(4))) float;

__device__ __forceinline__ unsigned short f2bf(float f) {
  __hip_bfloat16 h = __float2bfloat16(f);
  return __builtin_bit_cast(unsigned short, h);
}

// Map local tile row m (0..63) to a global x row such that rows 4*p..4*p+3 are
// the 2x2 pooling corners of pooled row bx*16+p.
__device__ __forceinline__ int pool_row(int bx, int m) {
  int pg = bx * 16 + (m >> 2);
  int corner = m & 3;
  int batch = pg >> 10;
  int pl = pg & 1023;
  int pi = pl >> 5, pj = pl & 31;
  return (batch << 12) + ((2 * pi + (corner >> 1)) << 6) + 2 * pj + (corner & 1);
}

// Pack weights: wcatT[384][512] = [f(64) | g(64) | h(256)]^T bf16; woT[512][256] bf16.
__global__ __launch_bounds__(256) void pack_w(const float* __restrict__ wf,
                                              const float* __restrict__ wg,
                                              const float* __restrict__ wh,
                                              const float* __restrict__ wo,
                                              unsigned short* __restrict__ wcatT,
                                              unsigned short* __restrict__ woT) {
  int i = blockIdx.x * 256 + threadIdx.x;
  if (i < 384 * 512) {
    int n = i >> 9, k = i & 511;
    float v = (n < 64) ? wf[k * 64 + n]
            : (n < 128) ? wg[k * 64 + (n - 64)]
                        : wh[k * 256 + (n - 128)];
    wcatT[i] = f2bf(v);
  } else if (i < 384 * 512 + 512 * 256) {
    int j = i - 384 * 512;
    int n = j >> 8, k = j & 255;
    woT[j] = f2bf(wo[(size_t)k * 512 + n]);
  }
}

// Fused f/g/h projection, MFMA. (R5-best form, unchanged.)
// 512 thr / 8 waves, block tile 64 rows x 384 cols (wave tile 64x48),
// grid 512 -> 2 blocks/CU, per-chunk staging.
__global__ __launch_bounds__(512) void fgh_proj(const float* __restrict__ x,
                                                const unsigned short* __restrict__ wcatT,
                                                unsigned short* __restrict__ fB,
                                                unsigned short* __restrict__ gB,
                                                unsigned short* __restrict__ hT) {
  __shared__ unsigned short lds[17920];  // As[64][40] @0 ; WsT[384][40] @2560
  const int tid = threadIdx.x;
  const int bx = blockIdx.x;
  const int wave = tid >> 6, lane = tid & 63;
  const int col = lane & 15, rgrp = lane >> 4;
  const int wcol = wave * 48;

  f32x4 acc[4][3];
#pragma unroll
  for (int mt = 0; mt < 4; ++mt)
#pragma unroll
    for (int nt = 0; nt < 3; ++nt) acc[mt][nt] = (f32x4){0.f, 0.f, 0.f, 0.f};

  for (int kt = 0; kt < 16; ++kt) {
    __syncthreads();
    {  // x: 64 rows x 32 k, cvt to bf16 (512 float4, 1/thread)
      int m = tid >> 3, k4 = (tid & 7) << 2;
      float4 v = *(const float4*)(x + (size_t)pool_row(bx, m) * 512 + kt * 32 + k4);
      ushort4 o4;
      o4.x = f2bf(v.x); o4.y = f2bf(v.y); o4.z = f2bf(v.z); o4.w = f2bf(v.w);
      *(ushort4*)&lds[m * 40 + k4] = o4;
    }
#pragma unroll
    for (int r = 0; r < 3; ++r) {  // wcatT: 384 n x 32 k (1536 uint4, 3/thread)
      int idx = tid + r * 512;
      int n = idx >> 2, k8 = (idx & 3) << 3;
      *(uint4*)&lds[2560 + n * 40 + k8] =
          *(const uint4*)(wcatT + (size_t)n * 512 + kt * 32 + k8);
    }
    __syncthreads();

    short8 am[4];
#pragma unroll
    for (int mt = 0; mt < 4; ++mt)
      am[mt] = *(const short8*)&lds[(mt * 16 + col) * 40 + rgrp * 8];
#pragma unroll
    for (int nt = 0; nt < 3; ++nt) {
      short8 bn = *(const short8*)&lds[2560 + (wcol + nt * 16 + col) * 40 + rgrp * 8];
#pragma unroll
      for (int mt = 0; mt < 4; ++mt)
        acc[mt][nt] = __builtin_amdgcn_mfma_f32_16x16x32_bf16(am[mt], bn, acc[mt][nt], 0, 0, 0);
    }
  }
  __syncthreads();

  // epilogue assembly in LDS (alias over staging)
  unsigned short* gO = lds;          // [64][72]
  unsigned short* fO = lds + 4608;   // [16][72]
  unsigned short* hO = lds + 5760;   // [256][24]
#pragma unroll
  for (int mt = 0; mt < 4; ++mt) {
#pragma unroll
    for (int nt = 0; nt < 3; ++nt) {
      int n = wcol + nt * 16 + col;
      f32x4 a = acc[mt][nt];
      if (n < 64) {
        float mx = fmaxf(fmaxf(a[0], a[1]), fmaxf(a[2], a[3]));
        fO[(mt * 4 + rgrp) * 72 + n] = f2bf(mx);
      } else if (n < 128) {
#pragma unroll
        for (int reg = 0; reg < 4; ++reg)
          gO[(mt * 16 + rgrp * 4 + reg) * 72 + (n - 64)] = f2bf(a[reg]);
      } else {
        float mx = fmaxf(fmaxf(a[0], a[1]), fmaxf(a[2], a[3]));
        hO[(n - 128) * 24 + (mt * 4 + rgrp)] = f2bf(mx);
      }
    }
  }
  __syncthreads();

  const int b = bx >> 6, pkb = (bx & 63) * 16;
  {
    int m = tid >> 3, d8 = (tid & 7) << 3;
    *(uint4*)(gB + (size_t)pool_row(bx, m) * 64 + d8) = *(const uint4*)&gO[m * 72 + d8];
  }
  if (tid < 128) {
    int pr = tid >> 3, d8 = (tid & 7) << 3;
    *(uint4*)(fB + (size_t)(bx * 16 + pr) * 64 + d8) = *(const uint4*)&fO[pr * 72 + d8];
  }
  {
    int dv = tid >> 1, p8 = (tid & 1) << 3;
    *(uint4*)(hT + (((size_t)b * 256 + dv) << 10) + pkb + p8) = *(const uint4*)&hO[dv * 24 + p8];
  }
}

// MFMA flash attention; bf16 output o[32768][256].
// v6: ZERO in-loop barriers. F/H per batch = 640 KB -> L2-resident per XCD and
// re-read by all 32 q-blocks of the batch; staging it in LDS was pure overhead
// (guide: L2-fit rule). QK^T and PV B-fragments load directly from global
// (L2 hits); pS stays wave-private LDS; Q in registers. The compiler can now
// pipeline next-chunk loads across iterations (no barrier in the way).
__global__ __launch_bounds__(512) void attn_mfma(const __hip_bfloat16* __restrict__ G,
                                                 const __hip_bfloat16* __restrict__ F,
                                                 const __hip_bfloat16* __restrict__ HT,
                                                 unsigned short* __restrict__ O) {
  // loop: pS[128][72] @0 (9216 ush, wave-private rows)
  // epilogue alias: oS[128][264] @0 (33792 ush = 67584 B)
  __shared__ unsigned short lds[33792];

  const int tid = threadIdx.x;
  const int wave = tid >> 6, lane = tid & 63;
  const int col = lane & 15;
  const int rgrp = lane >> 4;
  const int b = blockIdx.x >> 5, qt = blockIdx.x & 31;

  const unsigned short* Gb = (const unsigned short*)G + ((size_t)b * NTOK + qt * 128) * 64;
  const unsigned short* Fb = (const unsigned short*)F + (size_t)b * NPOOL * 64;
  const unsigned short* Hb = (const unsigned short*)HT + (size_t)b * 256 * NPOOL;

  // Q fragment straight from global (read once); wave w owns q-rows w*16..w*16+15
  short8 ag[2];
#pragma unroll
  for (int ks = 0; ks < 2; ++ks)
    ag[ks] = *(const short8*)(Gb + (size_t)(wave * 16 + col) * 64 + ks * 32 + rgrp * 8);

  f32x4 oacc[16];
#pragma unroll
  for (int t = 0; t < 16; ++t) oacc[t] = (f32x4){0.f, 0.f, 0.f, 0.f};
  float m_run[4], l_run[4];
#pragma unroll
  for (int r = 0; r < 4; ++r) { m_run[r] = -1e30f; l_run[r] = 0.f; }

  for (int kc = 0; kc < 16; ++kc) {
    // QK^T — F fragments direct from L2
    f32x4 s[4];
#pragma unroll
    for (int t = 0; t < 4; ++t) s[t] = (f32x4){0.f, 0.f, 0.f, 0.f};
#pragma unroll
    for (int ks = 0; ks < 2; ++ks) {
#pragma unroll
      for (int t = 0; t < 4; ++t) {
        short8 bf = *(const short8*)(Fb + (size_t)(kc * 64 + t * 16 + col) * 64 + ks * 32 + rgrp * 8);
        s[t] = __builtin_amdgcn_mfma_f32_16x16x32_bf16(ag[ks], bf, s[t], 0, 0, 0);
      }
    }

    // online softmax with exact defer-rescale
    float cm[4];
#pragma unroll
    for (int r = 0; r < 4; ++r) {
      cm[r] = fmaxf(fmaxf(s[0][r], s[1][r]), fmaxf(s[2][r], s[3][r]));
#pragma unroll
      for (int msk = 1; msk < 16; msk <<= 1) cm[r] = fmaxf(cm[r], __shfl_xor(cm[r], msk));
    }
    bool upd = false;
#pragma unroll
    for (int r = 0; r < 4; ++r) upd |= (cm[r] > m_run[r]);
    if (__any(upd)) {
      float alpha[4];
#pragma unroll
      for (int r = 0; r < 4; ++r) {
        float mn = fmaxf(m_run[r], cm[r]);
        alpha[r] = __expf(m_run[r] - mn);
        m_run[r] = mn;
        l_run[r] *= alpha[r];
      }
#pragma unroll
      for (int t = 0; t < 16; ++t) {
#pragma unroll
        for (int r = 0; r < 4; ++r) oacc[t][r] *= alpha[r];
      }
    }

    float rs[4] = {0.f, 0.f, 0.f, 0.f};
    const int prow = wave * 16 + rgrp * 4;
#pragma unroll
    for (int t = 0; t < 4; ++t) {
#pragma unroll
      for (int r = 0; r < 4; ++r) {
        float p = __expf(s[t][r] - m_run[r]);
        rs[r] += p;
        lds[(prow + r) * 72 + t * 16 + col] = f2bf(p);
      }
    }
#pragma unroll
    for (int r = 0; r < 4; ++r) {
#pragma unroll
      for (int msk = 1; msk < 16; msk <<= 1) rs[r] += __shfl_xor(rs[r], msk);
      l_run[r] += rs[r];
    }

    // PV — H fragments direct from L2 (pS is wave-private: no barrier)
    short8 ap[2];
#pragma unroll
    for (int ks = 0; ks < 2; ++ks)
      ap[ks] = *(const short8*)&lds[(wave * 16 + col) * 72 + ks * 32 + rgrp * 8];
#pragma unroll
    for (int t = 0; t < 16; ++t) {
#pragma unroll
      for (int ks = 0; ks < 2; ++ks) {
        short8 bh = *(const short8*)(Hb + (size_t)(t * 16 + col) * NPOOL + kc * 64 + ks * 32 + rgrp * 8);
        oacc[t] = __builtin_amdgcn_mfma_f32_16x16x32_bf16(ap[ks], bh, oacc[t], 0, 0, 0);
      }
    }
  }

  // epilogue: normalize, assemble bf16 in LDS (oS aliases pS: barrier first)
  float inv[4];
#pragma unroll
  for (int r = 0; r < 4; ++r) inv[r] = 1.0f / l_run[r];
  __syncthreads();
  const int qrow = wave * 16 + rgrp * 4;
#pragma unroll
  for (int t = 0; t < 16; ++t) {
#pragma unroll
    for (int r = 0; r < 4; ++r)
      lds[(qrow + r) * 264 + t * 16 + col] = f2bf(oacc[t][r] * inv[r]);
  }
  __syncthreads();
  unsigned short* Ob = O + ((size_t)b * NTOK + qt * 128) * 256;
#pragma unroll
  for (int r = 0; r < 8; ++r) {
    int idx = tid + r * 512;
    int q = idx >> 5, d8 = (idx & 31) << 3;
    *(uint4*)(Ob + (size_t)q * 256 + d8) = *(const uint4*)&lds[q * 264 + d8];
  }
}

// MFMA out-GEMM: out = gamma*(o @ wo) + x. (R5-best form, unchanged.)
// 512 threads / 8 waves, block tile 64 rows x 512 cols (wave tile 64x64).
__global__ __launch_bounds__(512) void gemm_out_mfma(const unsigned short* __restrict__ Obf,
                                                     const unsigned short* __restrict__ woT,
                                                     const float* __restrict__ Xres,
                                                     const float* __restrict__ gamma,
                                                     float* __restrict__ Out) {
  __shared__ unsigned short lds[23040];  // As[64][40] @0 ; WsT[512][40] @2560
  const int tid = threadIdx.x;
  const int bx = blockIdx.x;
  const int wave = tid >> 6, lane = tid & 63;
  const int col = lane & 15, rgrp = lane >> 4;
  const int wc = wave * 64;

  f32x4 acc[4][4];
#pragma unroll
  for (int mt = 0; mt < 4; ++mt)
#pragma unroll
    for (int nt = 0; nt < 4; ++nt) acc[mt][nt] = (f32x4){0.f, 0.f, 0.f, 0.f};

  for (int kt = 0; kt < 8; ++kt) {
    __syncthreads();
    if (tid < 256) {  // A: 64 rows x 32 k (256 uint4)
      int m = tid >> 2, k8 = (tid & 3) << 3;
      *(uint4*)&lds[m * 40 + k8] =
          *(const uint4*)(Obf + ((size_t)bx * 64 + m) * 256 + kt * 32 + k8);
    }
#pragma unroll
    for (int r = 0; r < 4; ++r) {  // B: 512 n x 32 k (2048 uint4, 4/thread)
      int idx = tid + r * 512;
      int n = idx >> 2, k8 = (idx & 3) << 3;
      *(uint4*)&lds[2560 + n * 40 + k8] =
          *(const uint4*)(woT + (size_t)n * 256 + kt * 32 + k8);
    }
    __syncthreads();

    short8 am[4];
#pragma unroll
    for (int mt = 0; mt < 4; ++mt)
      am[mt] = *(const short8*)&lds[(mt * 16 + col) * 40 + rgrp * 8];
#pragma unroll
    for (int nt = 0; nt < 4; ++nt) {
      short8 bn = *(const short8*)&lds[2560 + (wc + nt * 16 + col) * 40 + rgrp * 8];
#pragma unroll
      for (int mt = 0; mt < 4; ++mt)
        acc[mt][nt] = __builtin_amdgcn_mfma_f32_16x16x32_bf16(am[mt], bn, acc[mt][nt], 0, 0, 0);
    }
  }

  float gm = gamma[0];
#pragma unroll
  for (int mt = 0; mt < 4; ++mt) {
#pragma unroll
    for (int nt = 0; nt < 4; ++nt) {
      int n = wc + nt * 16 + col;
#pragma unroll
      for (int reg = 0; reg < 4; ++reg) {
        size_t row = (size_t)bx * 64 + mt * 16 + rgrp * 4 + reg;
        size_t off = row * 512 + n;
        Out[off] = gm * acc[mt][nt][reg] + Xres[off];
      }
    }
  }
}

extern "C" void kernel_launch(void* const* d_in, const int* in_sizes, int n_in,
                              void* d_out, int out_size, void* d_ws, size_t ws_size,
                              hipStream_t stream) {
  (void)in_sizes; (void)n_in; (void)out_size; (void)ws_size;
  const float* x     = (const float*)d_in[0];
  const float* wf    = (const float*)d_in[1];
  const float* wg    = (const float*)d_in[2];
  const float* wh    = (const float*)d_in[3];
  const float* wo    = (const float*)d_in[4];
  const float* gamma = (const float*)d_in[5];
  float* out = (float*)d_out;

  unsigned short* ws = (unsigned short*)d_ws;
  unsigned short* oB    = ws;               // [32768][256] bf16
  unsigned short* gB    = ws + 8388608;     // [32768][64]
  unsigned short* fB    = ws + 10485760;    // [8192][64]
  unsigned short* hT    = ws + 11010048;    // [8][256][1024]
  unsigned short* wcatT = ws + 13107200;    // [384][512]
  unsigned short* woT   = ws + 13303808;    // [512][256]

  pack_w<<<1280, dim3(256), 0, stream>>>(wf, wg, wh, wo, wcatT, woT);
  fgh_proj<<<512, dim3(512), 0, stream>>>(x, wcatT, fB, gB, hT);
  attn_mfma<<<256, dim3(512), 0, stream>>>((const __hip_bfloat16*)gB, (const __hip_bfloat16*)fB,
                                           (const __hip_bfloat16*)hT, oB);
  gemm_out_mfma<<<512, dim3(512), 0, stream>>>(oB, woT, x, gamma, out);
}

// Round 12
// 221.940 us; speedup vs baseline: 1.9447x; 1.6248x over previous
//
#include <hip/hip_runtime.h>
#include <hip/hip_bf16.h>

#define NTOK 4096   // 64*64 tokens per batch
#define NPOOL 1024  // 32*32 pooled tokens per batch

using short8 = __attribute__((ext_vector_type(8))) short;
using f32x4  = __attribute__((ext_vector_type(4))) float;

__device__ __forceinline__ unsigned short f2bf(float f) {
  __hip_bfloat16 h = __float2bfloat16(f);
  return __builtin_bit_cast(unsigned short, h);
}

// Map local tile row m (0..63) to a global x row such that rows 4*p..4*p+3 are
// the 2x2 pooling corners of pooled row bx*16+p.
__device__ __forceinline__ int pool_row(int bx, int m) {
  int pg = bx * 16 + (m >> 2);
  int corner = m & 3;
  int batch = pg >> 10;
  int pl = pg & 1023;
  int pi = pl >> 5, pj = pl & 31;
  return (batch << 12) + ((2 * pi + (corner >> 1)) << 6) + 2 * pj + (corner & 1);
}

// Pack weights: wcatT[384][512] = [f(64) | g(64) | h(256)]^T bf16; woT[512][256] bf16.
__global__ __launch_bounds__(256) void pack_w(const float* __restrict__ wf,
                                              const float* __restrict__ wg,
                                              const float* __restrict__ wh,
                                              const float* __restrict__ wo,
                                              unsigned short* __restrict__ wcatT,
                                              unsigned short* __restrict__ woT) {
  int i = blockIdx.x * 256 + threadIdx.x;
  if (i < 384 * 512) {
    int n = i >> 9, k = i & 511;
    float v = (n < 64) ? wf[k * 64 + n]
            : (n < 128) ? wg[k * 64 + (n - 64)]
                        : wh[k * 256 + (n - 128)];
    wcatT[i] = f2bf(v);
  } else if (i < 384 * 512 + 512 * 256) {
    int j = i - 384 * 512;
    int n = j >> 8, k = j & 255;
    woT[j] = f2bf(wo[(size_t)k * 512 + n]);
  }
}

// Fused f/g/h projection, MFMA. (R5-best form, unchanged.)
__global__ __launch_bounds__(512) void fgh_proj(const float* __restrict__ x,
                                                const unsigned short* __restrict__ wcatT,
                                                unsigned short* __restrict__ fB,
                                                unsigned short* __restrict__ gB,
                                                unsigned short* __restrict__ hT) {
  __shared__ unsigned short lds[17920];  // As[64][40] @0 ; WsT[384][40] @2560
  const int tid = threadIdx.x;
  const int bx = blockIdx.x;
  const int wave = tid >> 6, lane = tid & 63;
  const int col = lane & 15, rgrp = lane >> 4;
  const int wcol = wave * 48;

  f32x4 acc[4][3];
#pragma unroll
  for (int mt = 0; mt < 4; ++mt)
#pragma unroll
    for (int nt = 0; nt < 3; ++nt) acc[mt][nt] = (f32x4){0.f, 0.f, 0.f, 0.f};

  for (int kt = 0; kt < 16; ++kt) {
    __syncthreads();
    {  // x: 64 rows x 32 k, cvt to bf16 (512 float4, 1/thread)
      int m = tid >> 3, k4 = (tid & 7) << 2;
      float4 v = *(const float4*)(x + (size_t)pool_row(bx, m) * 512 + kt * 32 + k4);
      ushort4 o4;
      o4.x = f2bf(v.x); o4.y = f2bf(v.y); o4.z = f2bf(v.z); o4.w = f2bf(v.w);
      *(ushort4*)&lds[m * 40 + k4] = o4;
    }
#pragma unroll
    for (int r = 0; r < 3; ++r) {  // wcatT: 384 n x 32 k (1536 uint4, 3/thread)
      int idx = tid + r * 512;
      int n = idx >> 2, k8 = (idx & 3) << 3;
      *(uint4*)&lds[2560 + n * 40 + k8] =
          *(const uint4*)(wcatT + (size_t)n * 512 + kt * 32 + k8);
    }
    __syncthreads();

    short8 am[4];
#pragma unroll
    for (int mt = 0; mt < 4; ++mt)
      am[mt] = *(const short8*)&lds[(mt * 16 + col) * 40 + rgrp * 8];
#pragma unroll
    for (int nt = 0; nt < 3; ++nt) {
      short8 bn = *(const short8*)&lds[2560 + (wcol + nt * 16 + col) * 40 + rgrp * 8];
#pragma unroll
      for (int mt = 0; mt < 4; ++mt)
        acc[mt][nt] = __builtin_amdgcn_mfma_f32_16x16x32_bf16(am[mt], bn, acc[mt][nt], 0, 0, 0);
    }
  }
  __syncthreads();

  // epilogue assembly in LDS (alias over staging)
  unsigned short* gO = lds;          // [64][72]
  unsigned short* fO = lds + 4608;   // [16][72]
  unsigned short* hO = lds + 5760;   // [256][24]
#pragma unroll
  for (int mt = 0; mt < 4; ++mt) {
#pragma unroll
    for (int nt = 0; nt < 3; ++nt) {
      int n = wcol + nt * 16 + col;
      f32x4 a = acc[mt][nt];
      if (n < 64) {
        float mx = fmaxf(fmaxf(a[0], a[1]), fmaxf(a[2], a[3]));
        fO[(mt * 4 + rgrp) * 72 + n] = f2bf(mx);
      } else if (n < 128) {
#pragma unroll
        for (int reg = 0; reg < 4; ++reg)
          gO[(mt * 16 + rgrp * 4 + reg) * 72 + (n - 64)] = f2bf(a[reg]);
      } else {
        float mx = fmaxf(fmaxf(a[0], a[1]), fmaxf(a[2], a[3]));
        hO[(n - 128) * 24 + (mt * 4 + rgrp)] = f2bf(mx);
      }
    }
  }
  __syncthreads();

  const int b = bx >> 6, pkb = (bx & 63) * 16;
  {
    int m = tid >> 3, d8 = (tid & 7) << 3;
    *(uint4*)(gB + (size_t)pool_row(bx, m) * 64 + d8) = *(const uint4*)&gO[m * 72 + d8];
  }
  if (tid < 128) {
    int pr = tid >> 3, d8 = (tid & 7) << 3;
    *(uint4*)(fB + (size_t)(bx * 16 + pr) * 64 + d8) = *(const uint4*)&fO[pr * 72 + d8];
  }
  {
    int dv = tid >> 1, p8 = (tid & 1) << 3;
    *(uint4*)(hT + (((size_t)b * 256 + dv) << 10) + pkb + p8) = *(const uint4*)&hO[dv * 24 + p8];
  }
}

// MFMA flash attention; bf16 output o[32768][256].
// v7: R5 winner structure + 2-chunk-per-barrier staging. Each barrier pair
// stages 128 kv rows of F and 128 k-cols of H; then computes two 64-kv
// sub-chunks with no intervening barrier (pS is wave-private). Barrier
// events drop 32 -> 17; bytes, registers, MFMA schedule unchanged.
__global__ __launch_bounds__(512) void attn_mfma(const __hip_bfloat16* __restrict__ G,
                                                 const __hip_bfloat16* __restrict__ F,
                                                 const __hip_bfloat16* __restrict__ HT,
                                                 unsigned short* __restrict__ O) {
  // fS[128][72] @0 (9216) ; hS[256][136] @9216 (34816) ; pS[128][72] @44032 (9216)
  // total 53248 ush = 106496 B (1 block/CU, <160 KB)
  // epilogue alias: oS[128][264] @0 (33792 ush)
  __shared__ unsigned short lds[53248];

  const int tid = threadIdx.x;
  const int wave = tid >> 6, lane = tid & 63;
  const int col = lane & 15;
  const int rgrp = lane >> 4;
  const int b = blockIdx.x >> 5, qt = blockIdx.x & 31;

  const unsigned short* Gb = (const unsigned short*)G + ((size_t)b * NTOK + qt * 128) * 64;
  const unsigned short* Fb = (const unsigned short*)F + (size_t)b * NPOOL * 64;
  const unsigned short* Hb = (const unsigned short*)HT + (size_t)b * 256 * NPOOL;

  // Q fragment straight from global (read once); wave w owns q-rows w*16..w*16+15
  short8 ag[2];
#pragma unroll
  for (int ks = 0; ks < 2; ++ks)
    ag[ks] = *(const short8*)(Gb + (size_t)(wave * 16 + col) * 64 + ks * 32 + rgrp * 8);

  f32x4 oacc[16];
#pragma unroll
  for (int t = 0; t < 16; ++t) oacc[t] = (f32x4){0.f, 0.f, 0.f, 0.f};
  float m_run[4], l_run[4];
#pragma unroll
  for (int r = 0; r < 4; ++r) { m_run[r] = -1e30f; l_run[r] = 0.f; }

  // staging maps (constant per thread)
  const int fk = tid >> 3, fd8 = (tid & 7) << 3;     // F: 2 uint4/thread over 128 rows
  const int hdv = tid >> 4, hk8 = (tid & 15) << 3;   // H: 8 uint4/thread

  for (int sc = 0; sc < 8; ++sc) {  // superchunk = 128 kv rows
    __syncthreads();  // previous superchunk's LDS reads done
#pragma unroll
    for (int r = 0; r < 2; ++r) {  // F: 128 k-rows x 64 d
      int k = fk + r * 64;
      *(uint4*)&lds[k * 72 + fd8] =
          *(const uint4*)(Fb + (size_t)(sc * 128 + k) * 64 + fd8);
    }
#pragma unroll
    for (int r = 0; r < 8; ++r) {  // H: 256 dv-rows x 128 k
      int dv = hdv + r * 32;
      *(uint4*)&lds[9216 + dv * 136 + hk8] =
          *(const uint4*)(Hb + (size_t)dv * NPOOL + sc * 128 + hk8);
    }
    __syncthreads();  // data ready

#pragma unroll
    for (int half = 0; half < 2; ++half) {
      const int bk = half * 64;

      // QK^T
      f32x4 s[4];
#pragma unroll
      for (int t = 0; t < 4; ++t) s[t] = (f32x4){0.f, 0.f, 0.f, 0.f};
#pragma unroll
      for (int ks = 0; ks < 2; ++ks) {
#pragma unroll
        for (int t = 0; t < 4; ++t) {
          short8 bf = *(const short8*)&lds[(bk + t * 16 + col) * 72 + ks * 32 + rgrp * 8];
          s[t] = __builtin_amdgcn_mfma_f32_16x16x32_bf16(ag[ks], bf, s[t], 0, 0, 0);
        }
      }

      // online softmax with exact defer-rescale
      float cm[4];
#pragma unroll
      for (int r = 0; r < 4; ++r) {
        cm[r] = fmaxf(fmaxf(s[0][r], s[1][r]), fmaxf(s[2][r], s[3][r]));
#pragma unroll
        for (int msk = 1; msk < 16; msk <<= 1) cm[r] = fmaxf(cm[r], __shfl_xor(cm[r], msk));
      }
      bool upd = false;
#pragma unroll
      for (int r = 0; r < 4; ++r) upd |= (cm[r] > m_run[r]);
      if (__any(upd)) {
        float alpha[4];
#pragma unroll
        for (int r = 0; r < 4; ++r) {
          float mn = fmaxf(m_run[r], cm[r]);
          alpha[r] = __expf(m_run[r] - mn);
          m_run[r] = mn;
          l_run[r] *= alpha[r];
        }
#pragma unroll
        for (int t = 0; t < 16; ++t) {
#pragma unroll
          for (int r = 0; r < 4; ++r) oacc[t][r] *= alpha[r];
        }
      }

      float rs[4] = {0.f, 0.f, 0.f, 0.f};
      const int prow = wave * 16 + rgrp * 4;
#pragma unroll
      for (int t = 0; t < 4; ++t) {
#pragma unroll
        for (int r = 0; r < 4; ++r) {
          float p = __expf(s[t][r] - m_run[r]);
          rs[r] += p;
          lds[44032 + (prow + r) * 72 + t * 16 + col] = f2bf(p);
        }
      }
#pragma unroll
      for (int r = 0; r < 4; ++r) {
#pragma unroll
        for (int msk = 1; msk < 16; msk <<= 1) rs[r] += __shfl_xor(rs[r], msk);
        l_run[r] += rs[r];
      }

      // PV (pS is wave-private: same-wave write->read needs no barrier)
      short8 ap[2];
#pragma unroll
      for (int ks = 0; ks < 2; ++ks)
        ap[ks] = *(const short8*)&lds[44032 + (wave * 16 + col) * 72 + ks * 32 + rgrp * 8];
#pragma unroll
      for (int t = 0; t < 16; ++t) {
#pragma unroll
        for (int ks = 0; ks < 2; ++ks) {
          short8 bh = *(const short8*)&lds[9216 + (t * 16 + col) * 136 + bk + ks * 32 + rgrp * 8];
          oacc[t] = __builtin_amdgcn_mfma_f32_16x16x32_bf16(ap[ks], bh, oacc[t], 0, 0, 0);
        }
      }
    }
  }

  // epilogue: normalize, assemble bf16 in LDS (alias @0), coalesced store
  float inv[4];
#pragma unroll
  for (int r = 0; r < 4; ++r) inv[r] = 1.0f / l_run[r];
  __syncthreads();
  const int qrow = wave * 16 + rgrp * 4;
#pragma unroll
  for (int t = 0; t < 16; ++t) {
#pragma unroll
    for (int r = 0; r < 4; ++r)
      lds[(qrow + r) * 264 + t * 16 + col] = f2bf(oacc[t][r] * inv[r]);
  }
  __syncthreads();
  unsigned short* Ob = O + ((size_t)b * NTOK + qt * 128) * 256;
#pragma unroll
  for (int r = 0; r < 8; ++r) {
    int idx = tid + r * 512;
    int q = idx >> 5, d8 = (idx & 31) << 3;
    *(uint4*)(Ob + (size_t)q * 256 + d8) = *(const uint4*)&lds[q * 264 + d8];
  }
}

// MFMA out-GEMM: out = gamma*(o @ wo) + x. (R5-best form, unchanged.)
__global__ __launch_bounds__(512) void gemm_out_mfma(const unsigned short* __restrict__ Obf,
                                                     const unsigned short* __restrict__ woT,
                                                     const float* __restrict__ Xres,
                                                     const float* __restrict__ gamma,
                                                     float* __restrict__ Out) {
  __shared__ unsigned short lds[23040];  // As[64][40] @0 ; WsT[512][40] @2560
  const int tid = threadIdx.x;
  const int bx = blockIdx.x;
  const int wave = tid >> 6, lane = tid & 63;
  const int col = lane & 15, rgrp = lane >> 4;
  const int wc = wave * 64;

  f32x4 acc[4][4];
#pragma unroll
  for (int mt = 0; mt < 4; ++mt)
#pragma unroll
    for (int nt = 0; nt < 4; ++nt) acc[mt][nt] = (f32x4){0.f, 0.f, 0.f, 0.f};

  for (int kt = 0; kt < 8; ++kt) {
    __syncthreads();
    if (tid < 256) {  // A: 64 rows x 32 k (256 uint4)
      int m = tid >> 2, k8 = (tid & 3) << 3;
      *(uint4*)&lds[m * 40 + k8] =
          *(const uint4*)(Obf + ((size_t)bx * 64 + m) * 256 + kt * 32 + k8);
    }
#pragma unroll
    for (int r = 0; r < 4; ++r) {  // B: 512 n x 32 k (2048 uint4, 4/thread)
      int idx = tid + r * 512;
      int n = idx >> 2, k8 = (idx & 3) << 3;
      *(uint4*)&lds[2560 + n * 40 + k8] =
          *(const uint4*)(woT + (size_t)n * 256 + kt * 32 + k8);
    }
    __syncthreads();

    short8 am[4];
#pragma unroll
    for (int mt = 0; mt < 4; ++mt)
      am[mt] = *(const short8*)&lds[(mt * 16 + col) * 40 + rgrp * 8];
#pragma unroll
    for (int nt = 0; nt < 4; ++nt) {
      short8 bn = *(const short8*)&lds[2560 + (wc + nt * 16 + col) * 40 + rgrp * 8];
#pragma unroll
      for (int mt = 0; mt < 4; ++mt)
        acc[mt][nt] = __builtin_amdgcn_mfma_f32_16x16x32_bf16(am[mt], bn, acc[mt][nt], 0, 0, 0);
    }
  }

  float gm = gamma[0];
#pragma unroll
  for (int mt = 0; mt < 4; ++mt) {
#pragma unroll
    for (int nt = 0; nt < 4; ++nt) {
      int n = wc + nt * 16 + col;
#pragma unroll
      for (int reg = 0; reg < 4; ++reg) {
        size_t row = (size_t)bx * 64 + mt * 16 + rgrp * 4 + reg;
        size_t off = row * 512 + n;
        Out[off] = gm * acc[mt][nt][reg] + Xres[off];
      }
    }
  }
}

extern "C" void kernel_launch(void* const* d_in, const int* in_sizes, int n_in,
                              void* d_out, int out_size, void* d_ws, size_t ws_size,
                              hipStream_t stream) {
  (void)in_sizes; (void)n_in; (void)out_size; (void)ws_size;
  const float* x     = (const float*)d_in[0];
  const float* wf    = (const float*)d_in[1];
  const float* wg    = (const float*)d_in[2];
  const float* wh    = (const float*)d_in[3];
  const float* wo    = (const float*)d_in[4];
  const float* gamma = (const float*)d_in[5];
  float* out = (float*)d_out;

  unsigned short* ws = (unsigned short*)d_ws;
  unsigned short* oB    = ws;               // [32768][256] bf16
  unsigned short* gB    = ws + 8388608;     // [32768][64]
  unsigned short* fB    = ws + 10485760;    // [8192][64]
  unsigned short* hT    = ws + 11010048;    // [8][256][1024]
  unsigned short* wcatT = ws + 13107200;    // [384][512]
  unsigned short* woT   = ws + 13303808;    // [512][256]

  pack_w<<<1280, dim3(256), 0, stream>>>(wf, wg, wh, wo, wcatT, woT);
  fgh_proj<<<512, dim3(512), 0, stream>>>(x, wcatT, fB, gB, hT);
  attn_mfma<<<256, dim3(512), 0, stream>>>((const __hip_bfloat16*)gB, (const __hip_bfloat16*)fB,
                                           (const __hip_bfloat16*)hT, oB);
  gemm_out_mfma<<<512, dim3(512), 0, stream>>>(oB, woT, x, gamma, out);
}

// Round 13
// 219.543 us; speedup vs baseline: 1.9659x; 1.0109x over previous
//
#include <hip/hip_runtime.h>
#include <hip/hip_bf16.h>

#define NTOK 4096   // 64*64 tokens per batch
#define NPOOL 1024  // 32*32 pooled tokens per batch

using short8 = __attribute__((ext_vector_type(8))) short;
using f32x4  = __attribute__((ext_vector_type(4))) float;

__device__ __forceinline__ unsigned short f2bf(float f) {
  __hip_bfloat16 h = __float2bfloat16(f);
  return __builtin_bit_cast(unsigned short, h);
}

// Map local tile row m (0..63) to a global x row such that rows 4*p..4*p+3 are
// the 2x2 pooling corners of pooled row bx*16+p.
__device__ __forceinline__ int pool_row(int bx, int m) {
  int pg = bx * 16 + (m >> 2);
  int corner = m & 3;
  int batch = pg >> 10;
  int pl = pg & 1023;
  int pi = pl >> 5, pj = pl & 31;
  return (batch << 12) + ((2 * pi + (corner >> 1)) << 6) + 2 * pj + (corner & 1);
}

// Pack weights: wcatT[384][512] = [f(64) | g(64) | h(256)]^T bf16; woT[512][256] bf16.
__global__ __launch_bounds__(256) void pack_w(const float* __restrict__ wf,
                                              const float* __restrict__ wg,
                                              const float* __restrict__ wh,
                                              const float* __restrict__ wo,
                                              unsigned short* __restrict__ wcatT,
                                              unsigned short* __restrict__ woT) {
  int i = blockIdx.x * 256 + threadIdx.x;
  if (i < 384 * 512) {
    int n = i >> 9, k = i & 511;
    float v = (n < 64) ? wf[k * 64 + n]
            : (n < 128) ? wg[k * 64 + (n - 64)]
                        : wh[k * 256 + (n - 128)];
    wcatT[i] = f2bf(v);
  } else if (i < 384 * 512 + 512 * 256) {
    int j = i - 384 * 512;
    int n = j >> 8, k = j & 255;
    woT[j] = f2bf(wo[(size_t)k * 512 + n]);
  }
}

// Fused f/g/h projection, MFMA. (R5-best form, unchanged.)
__global__ __launch_bounds__(512) void fgh_proj(const float* __restrict__ x,
                                                const unsigned short* __restrict__ wcatT,
                                                unsigned short* __restrict__ fB,
                                                unsigned short* __restrict__ gB,
                                                unsigned short* __restrict__ hT) {
  __shared__ unsigned short lds[17920];  // As[64][40] @0 ; WsT[384][40] @2560
  const int tid = threadIdx.x;
  const int bx = blockIdx.x;
  const int wave = tid >> 6, lane = tid & 63;
  const int col = lane & 15, rgrp = lane >> 4;
  const int wcol = wave * 48;

  f32x4 acc[4][3];
#pragma unroll
  for (int mt = 0; mt < 4; ++mt)
#pragma unroll
    for (int nt = 0; nt < 3; ++nt) acc[mt][nt] = (f32x4){0.f, 0.f, 0.f, 0.f};

  for (int kt = 0; kt < 16; ++kt) {
    __syncthreads();
    {  // x: 64 rows x 32 k, cvt to bf16 (512 float4, 1/thread)
      int m = tid >> 3, k4 = (tid & 7) << 2;
      float4 v = *(const float4*)(x + (size_t)pool_row(bx, m) * 512 + kt * 32 + k4);
      ushort4 o4;
      o4.x = f2bf(v.x); o4.y = f2bf(v.y); o4.z = f2bf(v.z); o4.w = f2bf(v.w);
      *(ushort4*)&lds[m * 40 + k4] = o4;
    }
#pragma unroll
    for (int r = 0; r < 3; ++r) {  // wcatT: 384 n x 32 k (1536 uint4, 3/thread)
      int idx = tid + r * 512;
      int n = idx >> 2, k8 = (idx & 3) << 3;
      *(uint4*)&lds[2560 + n * 40 + k8] =
          *(const uint4*)(wcatT + (size_t)n * 512 + kt * 32 + k8);
    }
    __syncthreads();

    short8 am[4];
#pragma unroll
    for (int mt = 0; mt < 4; ++mt)
      am[mt] = *(const short8*)&lds[(mt * 16 + col) * 40 + rgrp * 8];
#pragma unroll
    for (int nt = 0; nt < 3; ++nt) {
      short8 bn = *(const short8*)&lds[2560 + (wcol + nt * 16 + col) * 40 + rgrp * 8];
#pragma unroll
      for (int mt = 0; mt < 4; ++mt)
        acc[mt][nt] = __builtin_amdgcn_mfma_f32_16x16x32_bf16(am[mt], bn, acc[mt][nt], 0, 0, 0);
    }
  }
  __syncthreads();

  // epilogue assembly in LDS (alias over staging)
  unsigned short* gO = lds;          // [64][72]
  unsigned short* fO = lds + 4608;   // [16][72]
  unsigned short* hO = lds + 5760;   // [256][24]
#pragma unroll
  for (int mt = 0; mt < 4; ++mt) {
#pragma unroll
    for (int nt = 0; nt < 3; ++nt) {
      int n = wcol + nt * 16 + col;
      f32x4 a = acc[mt][nt];
      if (n < 64) {
        float mx = fmaxf(fmaxf(a[0], a[1]), fmaxf(a[2], a[3]));
        fO[(mt * 4 + rgrp) * 72 + n] = f2bf(mx);
      } else if (n < 128) {
#pragma unroll
        for (int reg = 0; reg < 4; ++reg)
          gO[(mt * 16 + rgrp * 4 + reg) * 72 + (n - 64)] = f2bf(a[reg]);
      } else {
        float mx = fmaxf(fmaxf(a[0], a[1]), fmaxf(a[2], a[3]));
        hO[(n - 128) * 24 + (mt * 4 + rgrp)] = f2bf(mx);
      }
    }
  }
  __syncthreads();

  const int b = bx >> 6, pkb = (bx & 63) * 16;
  {
    int m = tid >> 3, d8 = (tid & 7) << 3;
    *(uint4*)(gB + (size_t)pool_row(bx, m) * 64 + d8) = *(const uint4*)&gO[m * 72 + d8];
  }
  if (tid < 128) {
    int pr = tid >> 3, d8 = (tid & 7) << 3;
    *(uint4*)(fB + (size_t)(bx * 16 + pr) * 64 + d8) = *(const uint4*)&fO[pr * 72 + d8];
  }
  {
    int dv = tid >> 1, p8 = (tid & 1) << 3;
    *(uint4*)(hT + (((size_t)b * 256 + dv) << 10) + pkb + p8) = *(const uint4*)&hO[dv * 24 + p8];
  }
}

// MFMA flash attention; bf16 output o[32768][256].
// v8: R12 winner (superchunk=128, 17 barriers) + two exact VALU cuts:
//  (1) per-lane partial l-sum, cross-lane reduced ONCE in epilogue
//      (deletes 512 shfl+add per thread from the serial softmax chain);
//  (2) s_setprio(1) around MFMA clusters (T5: +4-7% on attn structures).
__global__ __launch_bounds__(512) void attn_mfma(const __hip_bfloat16* __restrict__ G,
                                                 const __hip_bfloat16* __restrict__ F,
                                                 const __hip_bfloat16* __restrict__ HT,
                                                 unsigned short* __restrict__ O) {
  // fS[128][72] @0 (9216) ; hS[256][136] @9216 (34816) ; pS[128][72] @44032 (9216)
  // total 53248 ush = 106496 B (1 block/CU)
  // epilogue alias: oS[128][264] @0 (33792 ush)
  __shared__ unsigned short lds[53248];

  const int tid = threadIdx.x;
  const int wave = tid >> 6, lane = tid & 63;
  const int col = lane & 15;
  const int rgrp = lane >> 4;
  const int b = blockIdx.x >> 5, qt = blockIdx.x & 31;

  const unsigned short* Gb = (const unsigned short*)G + ((size_t)b * NTOK + qt * 128) * 64;
  const unsigned short* Fb = (const unsigned short*)F + (size_t)b * NPOOL * 64;
  const unsigned short* Hb = (const unsigned short*)HT + (size_t)b * 256 * NPOOL;

  // Q fragment straight from global (read once); wave w owns q-rows w*16..w*16+15
  short8 ag[2];
#pragma unroll
  for (int ks = 0; ks < 2; ++ks)
    ag[ks] = *(const short8*)(Gb + (size_t)(wave * 16 + col) * 64 + ks * 32 + rgrp * 8);

  f32x4 oacc[16];
#pragma unroll
  for (int t = 0; t < 16; ++t) oacc[t] = (f32x4){0.f, 0.f, 0.f, 0.f};
  float m_run[4], l_part[4];  // l_part: per-lane partial row-sum (reduced at end)
#pragma unroll
  for (int r = 0; r < 4; ++r) { m_run[r] = -1e30f; l_part[r] = 0.f; }

  // staging maps (constant per thread)
  const int fk = tid >> 3, fd8 = (tid & 7) << 3;     // F: 2 uint4/thread over 128 rows
  const int hdv = tid >> 4, hk8 = (tid & 15) << 3;   // H: 8 uint4/thread

  for (int sc = 0; sc < 8; ++sc) {  // superchunk = 128 kv rows
    __syncthreads();  // previous superchunk's LDS reads done
#pragma unroll
    for (int r = 0; r < 2; ++r) {  // F: 128 k-rows x 64 d
      int k = fk + r * 64;
      *(uint4*)&lds[k * 72 + fd8] =
          *(const uint4*)(Fb + (size_t)(sc * 128 + k) * 64 + fd8);
    }
#pragma unroll
    for (int r = 0; r < 8; ++r) {  // H: 256 dv-rows x 128 k
      int dv = hdv + r * 32;
      *(uint4*)&lds[9216 + dv * 136 + hk8] =
          *(const uint4*)(Hb + (size_t)dv * NPOOL + sc * 128 + hk8);
    }
    __syncthreads();  // data ready

#pragma unroll
    for (int half = 0; half < 2; ++half) {
      const int bk = half * 64;

      // QK^T
      f32x4 s[4];
#pragma unroll
      for (int t = 0; t < 4; ++t) s[t] = (f32x4){0.f, 0.f, 0.f, 0.f};
      __builtin_amdgcn_s_setprio(1);
#pragma unroll
      for (int ks = 0; ks < 2; ++ks) {
#pragma unroll
        for (int t = 0; t < 4; ++t) {
          short8 bf = *(const short8*)&lds[(bk + t * 16 + col) * 72 + ks * 32 + rgrp * 8];
          s[t] = __builtin_amdgcn_mfma_f32_16x16x32_bf16(ag[ks], bf, s[t], 0, 0, 0);
        }
      }
      __builtin_amdgcn_s_setprio(0);

      // online softmax with exact defer-rescale
      float cm[4];
#pragma unroll
      for (int r = 0; r < 4; ++r) {
        cm[r] = fmaxf(fmaxf(s[0][r], s[1][r]), fmaxf(s[2][r], s[3][r]));
#pragma unroll
        for (int msk = 1; msk < 16; msk <<= 1) cm[r] = fmaxf(cm[r], __shfl_xor(cm[r], msk));
      }
      bool upd = false;
#pragma unroll
      for (int r = 0; r < 4; ++r) upd |= (cm[r] > m_run[r]);
      if (__any(upd)) {
        float alpha[4];
#pragma unroll
        for (int r = 0; r < 4; ++r) {
          float mn = fmaxf(m_run[r], cm[r]);
          alpha[r] = __expf(m_run[r] - mn);
          m_run[r] = mn;
          l_part[r] *= alpha[r];  // alpha uniform within 16-lane group: exact
        }
#pragma unroll
        for (int t = 0; t < 16; ++t) {
#pragma unroll
          for (int r = 0; r < 4; ++r) oacc[t][r] *= alpha[r];
        }
      }

      const int prow = wave * 16 + rgrp * 4;
#pragma unroll
      for (int t = 0; t < 4; ++t) {
#pragma unroll
        for (int r = 0; r < 4; ++r) {
          float p = __expf(s[t][r] - m_run[r]);
          l_part[r] += p;  // per-lane partial; no per-chunk shuffle reduce
          lds[44032 + (prow + r) * 72 + t * 16 + col] = f2bf(p);
        }
      }

      // PV (pS is wave-private: same-wave write->read needs no barrier)
      short8 ap[2];
#pragma unroll
      for (int ks = 0; ks < 2; ++ks)
        ap[ks] = *(const short8*)&lds[44032 + (wave * 16 + col) * 72 + ks * 32 + rgrp * 8];
      __builtin_amdgcn_s_setprio(1);
#pragma unroll
      for (int t = 0; t < 16; ++t) {
#pragma unroll
        for (int ks = 0; ks < 2; ++ks) {
          short8 bh = *(const short8*)&lds[9216 + (t * 16 + col) * 136 + bk + ks * 32 + rgrp * 8];
          oacc[t] = __builtin_amdgcn_mfma_f32_16x16x32_bf16(ap[ks], bh, oacc[t], 0, 0, 0);
        }
      }
      __builtin_amdgcn_s_setprio(0);
    }
  }

  // final cross-lane l reduction (once) + normalize + store
  float inv[4];
#pragma unroll
  for (int r = 0; r < 4; ++r) {
#pragma unroll
    for (int msk = 1; msk < 16; msk <<= 1) l_part[r] += __shfl_xor(l_part[r], msk);
    inv[r] = 1.0f / l_part[r];
  }
  __syncthreads();
  const int qrow = wave * 16 + rgrp * 4;
#pragma unroll
  for (int t = 0; t < 16; ++t) {
#pragma unroll
    for (int r = 0; r < 4; ++r)
      lds[(qrow + r) * 264 + t * 16 + col] = f2bf(oacc[t][r] * inv[r]);
  }
  __syncthreads();
  unsigned short* Ob = O + ((size_t)b * NTOK + qt * 128) * 256;
#pragma unroll
  for (int r = 0; r < 8; ++r) {
    int idx = tid + r * 512;
    int q = idx >> 5, d8 = (idx & 31) << 3;
    *(uint4*)(Ob + (size_t)q * 256 + d8) = *(const uint4*)&lds[q * 264 + d8];
  }
}

// MFMA out-GEMM: out = gamma*(o @ wo) + x. (R5-best form, unchanged.)
__global__ __launch_bounds__(512) void gemm_out_mfma(const unsigned short* __restrict__ Obf,
                                                     const unsigned short* __restrict__ woT,
                                                     const float* __restrict__ Xres,
                                                     const float* __restrict__ gamma,
                                                     float* __restrict__ Out) {
  __shared__ unsigned short lds[23040];  // As[64][40] @0 ; WsT[512][40] @2560
  const int tid = threadIdx.x;
  const int bx = blockIdx.x;
  const int wave = tid >> 6, lane = tid & 63;
  const int col = lane & 15, rgrp = lane >> 4;
  const int wc = wave * 64;

  f32x4 acc[4][4];
#pragma unroll
  for (int mt = 0; mt < 4; ++mt)
#pragma unroll
    for (int nt = 0; nt < 4; ++nt) acc[mt][nt] = (f32x4){0.f, 0.f, 0.f, 0.f};

  for (int kt = 0; kt < 8; ++kt) {
    __syncthreads();
    if (tid < 256) {  // A: 64 rows x 32 k (256 uint4)
      int m = tid >> 2, k8 = (tid & 3) << 3;
      *(uint4*)&lds[m * 40 + k8] =
          *(const uint4*)(Obf + ((size_t)bx * 64 + m) * 256 + kt * 32 + k8);
    }
#pragma unroll
    for (int r = 0; r < 4; ++r) {  // B: 512 n x 32 k (2048 uint4, 4/thread)
      int idx = tid + r * 512;
      int n = idx >> 2, k8 = (idx & 3) << 3;
      *(uint4*)&lds[2560 + n * 40 + k8] =
          *(const uint4*)(woT + (size_t)n * 256 + kt * 32 + k8);
    }
    __syncthreads();

    short8 am[4];
#pragma unroll
    for (int mt = 0; mt < 4; ++mt)
      am[mt] = *(const short8*)&lds[(mt * 16 + col) * 40 + rgrp * 8];
#pragma unroll
    for (int nt = 0; nt < 4; ++nt) {
      short8 bn = *(const short8*)&lds[2560 + (wc + nt * 16 + col) * 40 + rgrp * 8];
#pragma unroll
      for (int mt = 0; mt < 4; ++mt)
        acc[mt][nt] = __builtin_amdgcn_mfma_f32_16x16x32_bf16(am[mt], bn, acc[mt][nt], 0, 0, 0);
    }
  }

  float gm = gamma[0];
#pragma unroll
  for (int mt = 0; mt < 4; ++mt) {
#pragma unroll
    for (int nt = 0; nt < 4; ++nt) {
      int n = wc + nt * 16 + col;
#pragma unroll
      for (int reg = 0; reg < 4; ++reg) {
        size_t row = (size_t)bx * 64 + mt * 16 + rgrp * 4 + reg;
        size_t off = row * 512 + n;
        Out[off] = gm * acc[mt][nt][reg] + Xres[off];
      }
    }
  }
}

extern "C" void kernel_launch(void* const* d_in, const int* in_sizes, int n_in,
                              void* d_out, int out_size, void* d_ws, size_t ws_size,
                              hipStream_t stream) {
  (void)in_sizes; (void)n_in; (void)out_size; (void)ws_size;
  const float* x     = (const float*)d_in[0];
  const float* wf    = (const float*)d_in[1];
  const float* wg    = (const float*)d_in[2];
  const float* wh    = (const float*)d_in[3];
  const float* wo    = (const float*)d_in[4];
  const float* gamma = (const float*)d_in[5];
  float* out = (float*)d_out;

  unsigned short* ws = (unsigned short*)d_ws;
  unsigned short* oB    = ws;               // [32768][256] bf16
  unsigned short* gB    = ws + 8388608;     // [32768][64]
  unsigned short* fB    = ws + 10485760;    // [8192][64]
  unsigned short* hT    = ws + 11010048;    // [8][256][1024]
  unsigned short* wcatT = ws + 13107200;    // [384][512]
  unsigned short* woT   = ws + 13303808;    // [512][256]

  pack_w<<<1280, dim3(256), 0, stream>>>(wf, wg, wh, wo, wcatT, woT);
  fgh_proj<<<512, dim3(512), 0, stream>>>(x, wcatT, fB, gB, hT);
  attn_mfma<<<256, dim3(512), 0, stream>>>((const __hip_bfloat16*)gB, (const __hip_bfloat16*)fB,
                                           (const __hip_bfloat16*)hT, oB);
  gemm_out_mfma<<<512, dim3(512), 0, stream>>>(oB, woT, x, gamma, out);
}

// Round 14
// 217.369 us; speedup vs baseline: 1.9856x; 1.0100x over previous
//
#include <hip/hip_runtime.h>
#include <hip/hip_bf16.h>

#define NTOK 4096   // 64*64 tokens per batch
#define NPOOL 1024  // 32*32 pooled tokens per batch

using short8 = __attribute__((ext_vector_type(8))) short;
using f32x4  = __attribute__((ext_vector_type(4))) float;

__device__ __forceinline__ unsigned short f2bf(float f) {
  __hip_bfloat16 h = __float2bfloat16(f);
  return __builtin_bit_cast(unsigned short, h);
}

// Map local tile row m (0..63) to a global x row such that rows 4*p..4*p+3 are
// the 2x2 pooling corners of pooled row bx*16+p.
__device__ __forceinline__ int pool_row(int bx, int m) {
  int pg = bx * 16 + (m >> 2);
  int corner = m & 3;
  int batch = pg >> 10;
  int pl = pg & 1023;
  int pi = pl >> 5, pj = pl & 31;
  return (batch << 12) + ((2 * pi + (corner >> 1)) << 6) + 2 * pj + (corner & 1);
}

// Pack weights: wcatT[384][512] = [f(64) | g(64) | h(256)]^T bf16; woT[512][256] bf16.
__global__ __launch_bounds__(256) void pack_w(const float* __restrict__ wf,
                                              const float* __restrict__ wg,
                                              const float* __restrict__ wh,
                                              const float* __restrict__ wo,
                                              unsigned short* __restrict__ wcatT,
                                              unsigned short* __restrict__ woT) {
  int i = blockIdx.x * 256 + threadIdx.x;
  if (i < 384 * 512) {
    int n = i >> 9, k = i & 511;
    float v = (n < 64) ? wf[k * 64 + n]
            : (n < 128) ? wg[k * 64 + (n - 64)]
                        : wh[k * 256 + (n - 128)];
    wcatT[i] = f2bf(v);
  } else if (i < 384 * 512 + 512 * 256) {
    int j = i - 384 * 512;
    int n = j >> 8, k = j & 255;
    woT[j] = f2bf(wo[(size_t)k * 512 + n]);
  }
}

// Fused f/g/h projection, MFMA.
// v6: R5 structure + superchunk staging (R12 transform): stage 64 k-cols per
// barrier pair, compute two 32-k halves back-to-back. Barriers 32 -> 17.
// LDS 64.5 KB, still 2 blocks/CU (129 KB < 160 KB).
__global__ __launch_bounds__(512) void fgh_proj(const float* __restrict__ x,
                                                const unsigned short* __restrict__ wcatT,
                                                unsigned short* __restrict__ fB,
                                                unsigned short* __restrict__ gB,
                                                unsigned short* __restrict__ hT) {
  __shared__ unsigned short lds[32256];  // As[64][72] @0 ; Ws[384][72] @4608
  const int tid = threadIdx.x;
  const int bx = blockIdx.x;
  const int wave = tid >> 6, lane = tid & 63;
  const int col = lane & 15, rgrp = lane >> 4;
  const int wcol = wave * 48;

  f32x4 acc[4][3];
#pragma unroll
  for (int mt = 0; mt < 4; ++mt)
#pragma unroll
    for (int nt = 0; nt < 3; ++nt) acc[mt][nt] = (f32x4){0.f, 0.f, 0.f, 0.f};

  const int xm = tid >> 3, xk4 = (tid & 7) << 2;
  const float* xrow = x + (size_t)pool_row(bx, xm) * 512 + xk4;

  for (int sc = 0; sc < 8; ++sc) {  // superchunk = 64 k-columns
    __syncthreads();
#pragma unroll
    for (int r = 0; r < 2; ++r) {  // x: 64 rows x 64 k, cvt to bf16
      float4 v = *(const float4*)(xrow + sc * 64 + r * 32);
      ushort4 o4;
      o4.x = f2bf(v.x); o4.y = f2bf(v.y); o4.z = f2bf(v.z); o4.w = f2bf(v.w);
      *(ushort4*)&lds[xm * 72 + r * 32 + xk4] = o4;
    }
#pragma unroll
    for (int r = 0; r < 6; ++r) {  // wcatT: 384 n x 64 k (3072 uint4, 6/thread)
      int idx = tid + r * 512;
      int n = idx >> 3, c = idx & 7;
      *(uint4*)&lds[4608 + n * 72 + c * 8] =
          *(const uint4*)(wcatT + (size_t)n * 512 + sc * 64 + c * 8);
    }
    __syncthreads();

#pragma unroll
    for (int half = 0; half < 2; ++half) {
      short8 am[4];
#pragma unroll
      for (int mt = 0; mt < 4; ++mt)
        am[mt] = *(const short8*)&lds[(mt * 16 + col) * 72 + half * 32 + rgrp * 8];
#pragma unroll
      for (int nt = 0; nt < 3; ++nt) {
        short8 bn = *(const short8*)&lds[4608 + (wcol + nt * 16 + col) * 72 + half * 32 + rgrp * 8];
#pragma unroll
        for (int mt = 0; mt < 4; ++mt)
          acc[mt][nt] = __builtin_amdgcn_mfma_f32_16x16x32_bf16(am[mt], bn, acc[mt][nt], 0, 0, 0);
      }
    }
  }
  __syncthreads();

  // epilogue assembly in LDS (alias over staging)
  unsigned short* gO = lds;          // [64][72]
  unsigned short* fO = lds + 4608;   // [16][72]
  unsigned short* hO = lds + 5760;   // [256][24]
#pragma unroll
  for (int mt = 0; mt < 4; ++mt) {
#pragma unroll
    for (int nt = 0; nt < 3; ++nt) {
      int n = wcol + nt * 16 + col;
      f32x4 a = acc[mt][nt];
      if (n < 64) {
        float mx = fmaxf(fmaxf(a[0], a[1]), fmaxf(a[2], a[3]));
        fO[(mt * 4 + rgrp) * 72 + n] = f2bf(mx);
      } else if (n < 128) {
#pragma unroll
        for (int reg = 0; reg < 4; ++reg)
          gO[(mt * 16 + rgrp * 4 + reg) * 72 + (n - 64)] = f2bf(a[reg]);
      } else {
        float mx = fmaxf(fmaxf(a[0], a[1]), fmaxf(a[2], a[3]));
        hO[(n - 128) * 24 + (mt * 4 + rgrp)] = f2bf(mx);
      }
    }
  }
  __syncthreads();

  const int b = bx >> 6, pkb = (bx & 63) * 16;
  {
    int m = tid >> 3, d8 = (tid & 7) << 3;
    *(uint4*)(gB + (size_t)pool_row(bx, m) * 64 + d8) = *(const uint4*)&gO[m * 72 + d8];
  }
  if (tid < 128) {
    int pr = tid >> 3, d8 = (tid & 7) << 3;
    *(uint4*)(fB + (size_t)(bx * 16 + pr) * 64 + d8) = *(const uint4*)&fO[pr * 72 + d8];
  }
  {
    int dv = tid >> 1, p8 = (tid & 1) << 3;
    *(uint4*)(hT + (((size_t)b * 256 + dv) << 10) + pkb + p8) = *(const uint4*)&hO[dv * 24 + p8];
  }
}

// MFMA flash attention; bf16 output o[32768][256]. (R13 winner, unchanged.)
// superchunk=128 (17 barriers), per-lane partial l-sum, setprio around MFMA.
__global__ __launch_bounds__(512) void attn_mfma(const __hip_bfloat16* __restrict__ G,
                                                 const __hip_bfloat16* __restrict__ F,
                                                 const __hip_bfloat16* __restrict__ HT,
                                                 unsigned short* __restrict__ O) {
  // fS[128][72] @0 (9216) ; hS[256][136] @9216 (34816) ; pS[128][72] @44032 (9216)
  // total 53248 ush = 106496 B (1 block/CU)
  // epilogue alias: oS[128][264] @0 (33792 ush)
  __shared__ unsigned short lds[53248];

  const int tid = threadIdx.x;
  const int wave = tid >> 6, lane = tid & 63;
  const int col = lane & 15;
  const int rgrp = lane >> 4;
  const int b = blockIdx.x >> 5, qt = blockIdx.x & 31;

  const unsigned short* Gb = (const unsigned short*)G + ((size_t)b * NTOK + qt * 128) * 64;
  const unsigned short* Fb = (const unsigned short*)F + (size_t)b * NPOOL * 64;
  const unsigned short* Hb = (const unsigned short*)HT + (size_t)b * 256 * NPOOL;

  short8 ag[2];
#pragma unroll
  for (int ks = 0; ks < 2; ++ks)
    ag[ks] = *(const short8*)(Gb + (size_t)(wave * 16 + col) * 64 + ks * 32 + rgrp * 8);

  f32x4 oacc[16];
#pragma unroll
  for (int t = 0; t < 16; ++t) oacc[t] = (f32x4){0.f, 0.f, 0.f, 0.f};
  float m_run[4], l_part[4];
#pragma unroll
  for (int r = 0; r < 4; ++r) { m_run[r] = -1e30f; l_part[r] = 0.f; }

  const int fk = tid >> 3, fd8 = (tid & 7) << 3;
  const int hdv = tid >> 4, hk8 = (tid & 15) << 3;

  for (int sc = 0; sc < 8; ++sc) {
    __syncthreads();
#pragma unroll
    for (int r = 0; r < 2; ++r) {
      int k = fk + r * 64;
      *(uint4*)&lds[k * 72 + fd8] =
          *(const uint4*)(Fb + (size_t)(sc * 128 + k) * 64 + fd8);
    }
#pragma unroll
    for (int r = 0; r < 8; ++r) {
      int dv = hdv + r * 32;
      *(uint4*)&lds[9216 + dv * 136 + hk8] =
          *(const uint4*)(Hb + (size_t)dv * NPOOL + sc * 128 + hk8);
    }
    __syncthreads();

#pragma unroll
    for (int half = 0; half < 2; ++half) {
      const int bk = half * 64;

      f32x4 s[4];
#pragma unroll
      for (int t = 0; t < 4; ++t) s[t] = (f32x4){0.f, 0.f, 0.f, 0.f};
      __builtin_amdgcn_s_setprio(1);
#pragma unroll
      for (int ks = 0; ks < 2; ++ks) {
#pragma unroll
        for (int t = 0; t < 4; ++t) {
          short8 bf = *(const short8*)&lds[(bk + t * 16 + col) * 72 + ks * 32 + rgrp * 8];
          s[t] = __builtin_amdgcn_mfma_f32_16x16x32_bf16(ag[ks], bf, s[t], 0, 0, 0);
        }
      }
      __builtin_amdgcn_s_setprio(0);

      float cm[4];
#pragma unroll
      for (int r = 0; r < 4; ++r) {
        cm[r] = fmaxf(fmaxf(s[0][r], s[1][r]), fmaxf(s[2][r], s[3][r]));
#pragma unroll
        for (int msk = 1; msk < 16; msk <<= 1) cm[r] = fmaxf(cm[r], __shfl_xor(cm[r], msk));
      }
      bool upd = false;
#pragma unroll
      for (int r = 0; r < 4; ++r) upd |= (cm[r] > m_run[r]);
      if (__any(upd)) {
        float alpha[4];
#pragma unroll
        for (int r = 0; r < 4; ++r) {
          float mn = fmaxf(m_run[r], cm[r]);
          alpha[r] = __expf(m_run[r] - mn);
          m_run[r] = mn;
          l_part[r] *= alpha[r];
        }
#pragma unroll
        for (int t = 0; t < 16; ++t) {
#pragma unroll
          for (int r = 0; r < 4; ++r) oacc[t][r] *= alpha[r];
        }
      }

      const int prow = wave * 16 + rgrp * 4;
#pragma unroll
      for (int t = 0; t < 4; ++t) {
#pragma unroll
        for (int r = 0; r < 4; ++r) {
          float p = __expf(s[t][r] - m_run[r]);
          l_part[r] += p;
          lds[44032 + (prow + r) * 72 + t * 16 + col] = f2bf(p);
        }
      }

      short8 ap[2];
#pragma unroll
      for (int ks = 0; ks < 2; ++ks)
        ap[ks] = *(const short8*)&lds[44032 + (wave * 16 + col) * 72 + ks * 32 + rgrp * 8];
      __builtin_amdgcn_s_setprio(1);
#pragma unroll
      for (int t = 0; t < 16; ++t) {
#pragma unroll
        for (int ks = 0; ks < 2; ++ks) {
          short8 bh = *(const short8*)&lds[9216 + (t * 16 + col) * 136 + bk + ks * 32 + rgrp * 8];
          oacc[t] = __builtin_amdgcn_mfma_f32_16x16x32_bf16(ap[ks], bh, oacc[t], 0, 0, 0);
        }
      }
      __builtin_amdgcn_s_setprio(0);
    }
  }

  float inv[4];
#pragma unroll
  for (int r = 0; r < 4; ++r) {
#pragma unroll
    for (int msk = 1; msk < 16; msk <<= 1) l_part[r] += __shfl_xor(l_part[r], msk);
    inv[r] = 1.0f / l_part[r];
  }
  __syncthreads();
  const int qrow = wave * 16 + rgrp * 4;
#pragma unroll
  for (int t = 0; t < 16; ++t) {
#pragma unroll
    for (int r = 0; r < 4; ++r)
      lds[(qrow + r) * 264 + t * 16 + col] = f2bf(oacc[t][r] * inv[r]);
  }
  __syncthreads();
  unsigned short* Ob = O + ((size_t)b * NTOK + qt * 128) * 256;
#pragma unroll
  for (int r = 0; r < 8; ++r) {
    int idx = tid + r * 512;
    int q = idx >> 5, d8 = (idx & 31) << 3;
    *(uint4*)(Ob + (size_t)q * 256 + d8) = *(const uint4*)&lds[q * 264 + d8];
  }
}

// MFMA out-GEMM: out = gamma*(o @ wo) + x. (R5-best form, unchanged; at HBM floor.)
__global__ __launch_bounds__(512) void gemm_out_mfma(const unsigned short* __restrict__ Obf,
                                                     const unsigned short* __restrict__ woT,
                                                     const float* __restrict__ Xres,
                                                     const float* __restrict__ gamma,
                                                     float* __restrict__ Out) {
  __shared__ unsigned short lds[23040];  // As[64][40] @0 ; WsT[512][40] @2560
  const int tid = threadIdx.x;
  const int bx = blockIdx.x;
  const int wave = tid >> 6, lane = tid & 63;
  const int col = lane & 15, rgrp = lane >> 4;
  const int wc = wave * 64;

  f32x4 acc[4][4];
#pragma unroll
  for (int mt = 0; mt < 4; ++mt)
#pragma unroll
    for (int nt = 0; nt < 4; ++nt) acc[mt][nt] = (f32x4){0.f, 0.f, 0.f, 0.f};

  for (int kt = 0; kt < 8; ++kt) {
    __syncthreads();
    if (tid < 256) {  // A: 64 rows x 32 k (256 uint4)
      int m = tid >> 2, k8 = (tid & 3) << 3;
      *(uint4*)&lds[m * 40 + k8] =
          *(const uint4*)(Obf + ((size_t)bx * 64 + m) * 256 + kt * 32 + k8);
    }
#pragma unroll
    for (int r = 0; r < 4; ++r) {  // B: 512 n x 32 k (2048 uint4, 4/thread)
      int idx = tid + r * 512;
      int n = idx >> 2, k8 = (idx & 3) << 3;
      *(uint4*)&lds[2560 + n * 40 + k8] =
          *(const uint4*)(woT + (size_t)n * 256 + kt * 32 + k8);
    }
    __syncthreads();

    short8 am[4];
#pragma unroll
    for (int mt = 0; mt < 4; ++mt)
      am[mt] = *(const short8*)&lds[(mt * 16 + col) * 40 + rgrp * 8];
#pragma unroll
    for (int nt = 0; nt < 4; ++nt) {
      short8 bn = *(const short8*)&lds[2560 + (wc + nt * 16 + col) * 40 + rgrp * 8];
#pragma unroll
      for (int mt = 0; mt < 4; ++mt)
        acc[mt][nt] = __builtin_amdgcn_mfma_f32_16x16x32_bf16(am[mt], bn, acc[mt][nt], 0, 0, 0);
    }
  }

  float gm = gamma[0];
#pragma unroll
  for (int mt = 0; mt < 4; ++mt) {
#pragma unroll
    for (int nt = 0; nt < 4; ++nt) {
      int n = wc + nt * 16 + col;
#pragma unroll
      for (int reg = 0; reg < 4; ++reg) {
        size_t row = (size_t)bx * 64 + mt * 16 + rgrp * 4 + reg;
        size_t off = row * 512 + n;
        Out[off] = gm * acc[mt][nt][reg] + Xres[off];
      }
    }
  }
}

extern "C" void kernel_launch(void* const* d_in, const int* in_sizes, int n_in,
                              void* d_out, int out_size, void* d_ws, size_t ws_size,
                              hipStream_t stream) {
  (void)in_sizes; (void)n_in; (void)out_size; (void)ws_size;
  const float* x     = (const float*)d_in[0];
  const float* wf    = (const float*)d_in[1];
  const float* wg    = (const float*)d_in[2];
  const float* wh    = (const float*)d_in[3];
  const float* wo    = (const float*)d_in[4];
  const float* gamma = (const float*)d_in[5];
  float* out = (float*)d_out;

  unsigned short* ws = (unsigned short*)d_ws;
  unsigned short* oB    = ws;               // [32768][256] bf16
  unsigned short* gB    = ws + 8388608;     // [32768][64]
  unsigned short* fB    = ws + 10485760;    // [8192][64]
  unsigned short* hT    = ws + 11010048;    // [8][256][1024]
  unsigned short* wcatT = ws + 13107200;    // [384][512]
  unsigned short* woT   = ws + 13303808;    // [512][256]

  pack_w<<<1280, dim3(256), 0, stream>>>(wf, wg, wh, wo, wcatT, woT);
  fgh_proj<<<512, dim3(512), 0, stream>>>(x, wcatT, fB, gB, hT);
  attn_mfma<<<256, dim3(512), 0, stream>>>((const __hip_bfloat16*)gB, (const __hip_bfloat16*)fB,
                                           (const __hip_bfloat16*)hT, oB);
  gemm_out_mfma<<<512, dim3(512), 0, stream>>>(oB, woT, x, gamma, out);
}

// Round 15
// 213.952 us; speedup vs baseline: 2.0173x; 1.0160x over previous
//
#include <hip/hip_runtime.h>
#include <hip/hip_bf16.h>

#define NTOK 4096   // 64*64 tokens per batch
#define NPOOL 1024  // 32*32 pooled tokens per batch

using short8 = __attribute__((ext_vector_type(8))) short;
using f32x4  = __attribute__((ext_vector_type(4))) float;

__device__ __forceinline__ unsigned short f2bf(float f) {
  __hip_bfloat16 h = __float2bfloat16(f);
  return __builtin_bit_cast(unsigned short, h);
}

// Map local tile row m (0..63) to a global x row such that rows 4*p..4*p+3 are
// the 2x2 pooling corners of pooled row bx*16+p.
__device__ __forceinline__ int pool_row(int bx, int m) {
  int pg = bx * 16 + (m >> 2);
  int corner = m & 3;
  int batch = pg >> 10;
  int pl = pg & 1023;
  int pi = pl >> 5, pj = pl & 31;
  return (batch << 12) + ((2 * pi + (corner >> 1)) << 6) + 2 * pj + (corner & 1);
}

// Pack weights: wcatT[384][512] = [f(64) | g(64) | h(256)]^T bf16; woT[512][256] bf16.
__global__ __launch_bounds__(256) void pack_w(const float* __restrict__ wf,
                                              const float* __restrict__ wg,
                                              const float* __restrict__ wh,
                                              const float* __restrict__ wo,
                                              unsigned short* __restrict__ wcatT,
                                              unsigned short* __restrict__ woT) {
  int i = blockIdx.x * 256 + threadIdx.x;
  if (i < 384 * 512) {
    int n = i >> 9, k = i & 511;
    float v = (n < 64) ? wf[k * 64 + n]
            : (n < 128) ? wg[k * 64 + (n - 64)]
                        : wh[k * 256 + (n - 128)];
    wcatT[i] = f2bf(v);
  } else if (i < 384 * 512 + 512 * 256) {
    int j = i - 384 * 512;
    int n = j >> 8, k = j & 255;
    woT[j] = f2bf(wo[(size_t)k * 512 + n]);
  }
}

// Fused f/g/h projection, MFMA. (R14 winner form, unchanged.)
// Superchunk staging: 64 k-cols per barrier pair, two 32-k halves. 17 barriers.
__global__ __launch_bounds__(512) void fgh_proj(const float* __restrict__ x,
                                                const unsigned short* __restrict__ wcatT,
                                                unsigned short* __restrict__ fB,
                                                unsigned short* __restrict__ gB,
                                                unsigned short* __restrict__ hT) {
  __shared__ unsigned short lds[32256];  // As[64][72] @0 ; Ws[384][72] @4608
  const int tid = threadIdx.x;
  const int bx = blockIdx.x;
  const int wave = tid >> 6, lane = tid & 63;
  const int col = lane & 15, rgrp = lane >> 4;
  const int wcol = wave * 48;

  f32x4 acc[4][3];
#pragma unroll
  for (int mt = 0; mt < 4; ++mt)
#pragma unroll
    for (int nt = 0; nt < 3; ++nt) acc[mt][nt] = (f32x4){0.f, 0.f, 0.f, 0.f};

  const int xm = tid >> 3, xk4 = (tid & 7) << 2;
  const float* xrow = x + (size_t)pool_row(bx, xm) * 512 + xk4;

  for (int sc = 0; sc < 8; ++sc) {  // superchunk = 64 k-columns
    __syncthreads();
#pragma unroll
    for (int r = 0; r < 2; ++r) {  // x: 64 rows x 64 k, cvt to bf16
      float4 v = *(const float4*)(xrow + sc * 64 + r * 32);
      ushort4 o4;
      o4.x = f2bf(v.x); o4.y = f2bf(v.y); o4.z = f2bf(v.z); o4.w = f2bf(v.w);
      *(ushort4*)&lds[xm * 72 + r * 32 + xk4] = o4;
    }
#pragma unroll
    for (int r = 0; r < 6; ++r) {  // wcatT: 384 n x 64 k (3072 uint4, 6/thread)
      int idx = tid + r * 512;
      int n = idx >> 3, c = idx & 7;
      *(uint4*)&lds[4608 + n * 72 + c * 8] =
          *(const uint4*)(wcatT + (size_t)n * 512 + sc * 64 + c * 8);
    }
    __syncthreads();

#pragma unroll
    for (int half = 0; half < 2; ++half) {
      short8 am[4];
#pragma unroll
      for (int mt = 0; mt < 4; ++mt)
        am[mt] = *(const short8*)&lds[(mt * 16 + col) * 72 + half * 32 + rgrp * 8];
#pragma unroll
      for (int nt = 0; nt < 3; ++nt) {
        short8 bn = *(const short8*)&lds[4608 + (wcol + nt * 16 + col) * 72 + half * 32 + rgrp * 8];
#pragma unroll
        for (int mt = 0; mt < 4; ++mt)
          acc[mt][nt] = __builtin_amdgcn_mfma_f32_16x16x32_bf16(am[mt], bn, acc[mt][nt], 0, 0, 0);
      }
    }
  }
  __syncthreads();

  // epilogue assembly in LDS (alias over staging)
  unsigned short* gO = lds;          // [64][72]
  unsigned short* fO = lds + 4608;   // [16][72]
  unsigned short* hO = lds + 5760;   // [256][24]
#pragma unroll
  for (int mt = 0; mt < 4; ++mt) {
#pragma unroll
    for (int nt = 0; nt < 3; ++nt) {
      int n = wcol + nt * 16 + col;
      f32x4 a = acc[mt][nt];
      if (n < 64) {
        float mx = fmaxf(fmaxf(a[0], a[1]), fmaxf(a[2], a[3]));
        fO[(mt * 4 + rgrp) * 72 + n] = f2bf(mx);
      } else if (n < 128) {
#pragma unroll
        for (int reg = 0; reg < 4; ++reg)
          gO[(mt * 16 + rgrp * 4 + reg) * 72 + (n - 64)] = f2bf(a[reg]);
      } else {
        float mx = fmaxf(fmaxf(a[0], a[1]), fmaxf(a[2], a[3]));
        hO[(n - 128) * 24 + (mt * 4 + rgrp)] = f2bf(mx);
      }
    }
  }
  __syncthreads();

  const int b = bx >> 6, pkb = (bx & 63) * 16;
  {
    int m = tid >> 3, d8 = (tid & 7) << 3;
    *(uint4*)(gB + (size_t)pool_row(bx, m) * 64 + d8) = *(const uint4*)&gO[m * 72 + d8];
  }
  if (tid < 128) {
    int pr = tid >> 3, d8 = (tid & 7) << 3;
    *(uint4*)(fB + (size_t)(bx * 16 + pr) * 64 + d8) = *(const uint4*)&fO[pr * 72 + d8];
  }
  {
    int dv = tid >> 1, p8 = (tid & 1) << 3;
    *(uint4*)(hT + (((size_t)b * 256 + dv) << 10) + pkb + p8) = *(const uint4*)&hO[dv * 24 + p8];
  }
}

// MFMA flash attention; bf16 output o[32768][256].
// v9: R13/R14 winner + T13 defer-rescale THRESHOLD=8 (HK-validated): skip the
// 64-mul oacc rescale while the tile max grows by <= 8; P bounded by e^8,
// fp32 accum + relative-rounding bf16 P tolerate it; normalization exact.
__global__ __launch_bounds__(512) void attn_mfma(const __hip_bfloat16* __restrict__ G,
                                                 const __hip_bfloat16* __restrict__ F,
                                                 const __hip_bfloat16* __restrict__ HT,
                                                 unsigned short* __restrict__ O) {
  // fS[128][72] @0 (9216) ; hS[256][136] @9216 (34816) ; pS[128][72] @44032 (9216)
  // total 53248 ush = 106496 B (1 block/CU)
  // epilogue alias: oS[128][264] @0 (33792 ush)
  __shared__ unsigned short lds[53248];

  const int tid = threadIdx.x;
  const int wave = tid >> 6, lane = tid & 63;
  const int col = lane & 15;
  const int rgrp = lane >> 4;
  const int b = blockIdx.x >> 5, qt = blockIdx.x & 31;

  const unsigned short* Gb = (const unsigned short*)G + ((size_t)b * NTOK + qt * 128) * 64;
  const unsigned short* Fb = (const unsigned short*)F + (size_t)b * NPOOL * 64;
  const unsigned short* Hb = (const unsigned short*)HT + (size_t)b * 256 * NPOOL;

  short8 ag[2];
#pragma unroll
  for (int ks = 0; ks < 2; ++ks)
    ag[ks] = *(const short8*)(Gb + (size_t)(wave * 16 + col) * 64 + ks * 32 + rgrp * 8);

  f32x4 oacc[16];
#pragma unroll
  for (int t = 0; t < 16; ++t) oacc[t] = (f32x4){0.f, 0.f, 0.f, 0.f};
  float m_run[4], l_part[4];
#pragma unroll
  for (int r = 0; r < 4; ++r) { m_run[r] = -1e30f; l_part[r] = 0.f; }

  const int fk = tid >> 3, fd8 = (tid & 7) << 3;
  const int hdv = tid >> 4, hk8 = (tid & 15) << 3;

  for (int sc = 0; sc < 8; ++sc) {
    __syncthreads();
#pragma unroll
    for (int r = 0; r < 2; ++r) {
      int k = fk + r * 64;
      *(uint4*)&lds[k * 72 + fd8] =
          *(const uint4*)(Fb + (size_t)(sc * 128 + k) * 64 + fd8);
    }
#pragma unroll
    for (int r = 0; r < 8; ++r) {
      int dv = hdv + r * 32;
      *(uint4*)&lds[9216 + dv * 136 + hk8] =
          *(const uint4*)(Hb + (size_t)dv * NPOOL + sc * 128 + hk8);
    }
    __syncthreads();

#pragma unroll
    for (int half = 0; half < 2; ++half) {
      const int bk = half * 64;

      f32x4 s[4];
#pragma unroll
      for (int t = 0; t < 4; ++t) s[t] = (f32x4){0.f, 0.f, 0.f, 0.f};
      __builtin_amdgcn_s_setprio(1);
#pragma unroll
      for (int ks = 0; ks < 2; ++ks) {
#pragma unroll
        for (int t = 0; t < 4; ++t) {
          short8 bf = *(const short8*)&lds[(bk + t * 16 + col) * 72 + ks * 32 + rgrp * 8];
          s[t] = __builtin_amdgcn_mfma_f32_16x16x32_bf16(ag[ks], bf, s[t], 0, 0, 0);
        }
      }
      __builtin_amdgcn_s_setprio(0);

      float cm[4];
#pragma unroll
      for (int r = 0; r < 4; ++r) {
        cm[r] = fmaxf(fmaxf(s[0][r], s[1][r]), fmaxf(s[2][r], s[3][r]));
#pragma unroll
        for (int msk = 1; msk < 16; msk <<= 1) cm[r] = fmaxf(cm[r], __shfl_xor(cm[r], msk));
      }
      // T13: only rescale when the max has grown by more than THR=8.
      bool upd = false;
#pragma unroll
      for (int r = 0; r < 4; ++r) upd |= (cm[r] > m_run[r] + 8.0f);
      if (__any(upd)) {
        float alpha[4];
#pragma unroll
        for (int r = 0; r < 4; ++r) {
          float mn = fmaxf(m_run[r], cm[r]);
          alpha[r] = __expf(m_run[r] - mn);
          m_run[r] = mn;
          l_part[r] *= alpha[r];
        }
#pragma unroll
        for (int t = 0; t < 16; ++t) {
#pragma unroll
          for (int r = 0; r < 4; ++r) oacc[t][r] *= alpha[r];
        }
      }

      const int prow = wave * 16 + rgrp * 4;
#pragma unroll
      for (int t = 0; t < 4; ++t) {
#pragma unroll
        for (int r = 0; r < 4; ++r) {
          float p = __expf(s[t][r] - m_run[r]);  // bounded by e^8 under defer
          l_part[r] += p;
          lds[44032 + (prow + r) * 72 + t * 16 + col] = f2bf(p);
        }
      }

      short8 ap[2];
#pragma unroll
      for (int ks = 0; ks < 2; ++ks)
        ap[ks] = *(const short8*)&lds[44032 + (wave * 16 + col) * 72 + ks * 32 + rgrp * 8];
      __builtin_amdgcn_s_setprio(1);
#pragma unroll
      for (int t = 0; t < 16; ++t) {
#pragma unroll
        for (int ks = 0; ks < 2; ++ks) {
          short8 bh = *(const short8*)&lds[9216 + (t * 16 + col) * 136 + bk + ks * 32 + rgrp * 8];
          oacc[t] = __builtin_amdgcn_mfma_f32_16x16x32_bf16(ap[ks], bh, oacc[t], 0, 0, 0);
        }
      }
      __builtin_amdgcn_s_setprio(0);
    }
  }

  float inv[4];
#pragma unroll
  for (int r = 0; r < 4; ++r) {
#pragma unroll
    for (int msk = 1; msk < 16; msk <<= 1) l_part[r] += __shfl_xor(l_part[r], msk);
    inv[r] = 1.0f / l_part[r];
  }
  __syncthreads();
  const int qrow = wave * 16 + rgrp * 4;
#pragma unroll
  for (int t = 0; t < 16; ++t) {
#pragma unroll
    for (int r = 0; r < 4; ++r)
      lds[(qrow + r) * 264 + t * 16 + col] = f2bf(oacc[t][r] * inv[r]);
  }
  __syncthreads();
  unsigned short* Ob = O + ((size_t)b * NTOK + qt * 128) * 256;
#pragma unroll
  for (int r = 0; r < 8; ++r) {
    int idx = tid + r * 512;
    int q = idx >> 5, d8 = (idx & 31) << 3;
    *(uint4*)(Ob + (size_t)q * 256 + d8) = *(const uint4*)&lds[q * 264 + d8];
  }
}

// MFMA out-GEMM: out = gamma*(o @ wo) + x. (R5-best form, unchanged; at HBM floor.)
__global__ __launch_bounds__(512) void gemm_out_mfma(const unsigned short* __restrict__ Obf,
                                                     const unsigned short* __restrict__ woT,
                                                     const float* __restrict__ Xres,
                                                     const float* __restrict__ gamma,
                                                     float* __restrict__ Out) {
  __shared__ unsigned short lds[23040];  // As[64][40] @0 ; WsT[512][40] @2560
  const int tid = threadIdx.x;
  const int bx = blockIdx.x;
  const int wave = tid >> 6, lane = tid & 63;
  const int col = lane & 15, rgrp = lane >> 4;
  const int wc = wave * 64;

  f32x4 acc[4][4];
#pragma unroll
  for (int mt = 0; mt < 4; ++mt)
#pragma unroll
    for (int nt = 0; nt < 4; ++nt) acc[mt][nt] = (f32x4){0.f, 0.f, 0.f, 0.f};

  for (int kt = 0; kt < 8; ++kt) {
    __syncthreads();
    if (tid < 256) {  // A: 64 rows x 32 k (256 uint4)
      int m = tid >> 2, k8 = (tid & 3) << 3;
      *(uint4*)&lds[m * 40 + k8] =
          *(const uint4*)(Obf + ((size_t)bx * 64 + m) * 256 + kt * 32 + k8);
    }
#pragma unroll
    for (int r = 0; r < 4; ++r) {  // B: 512 n x 32 k (2048 uint4, 4/thread)
      int idx = tid + r * 512;
      int n = idx >> 2, k8 = (idx & 3) << 3;
      *(uint4*)&lds[2560 + n * 40 + k8] =
          *(const uint4*)(woT + (size_t)n * 256 + kt * 32 + k8);
    }
    __syncthreads();

    short8 am[4];
#pragma unroll
    for (int mt = 0; mt < 4; ++mt)
      am[mt] = *(const short8*)&lds[(mt * 16 + col) * 40 + rgrp * 8];
#pragma unroll
    for (int nt = 0; nt < 4; ++nt) {
      short8 bn = *(const short8*)&lds[2560 + (wc + nt * 16 + col) * 40 + rgrp * 8];
#pragma unroll
      for (int mt = 0; mt < 4; ++mt)
        acc[mt][nt] = __builtin_amdgcn_mfma_f32_16x16x32_bf16(am[mt], bn, acc[mt][nt], 0, 0, 0);
    }
  }

  float gm = gamma[0];
#pragma unroll
  for (int mt = 0; mt < 4; ++mt) {
#pragma unroll
    for (int nt = 0; nt < 4; ++nt) {
      int n = wc + nt * 16 + col;
#pragma unroll
      for (int reg = 0; reg < 4; ++reg) {
        size_t row = (size_t)bx * 64 + mt * 16 + rgrp * 4 + reg;
        size_t off = row * 512 + n;
        Out[off] = gm * acc[mt][nt][reg] + Xres[off];
      }
    }
  }
}

extern "C" void kernel_launch(void* const* d_in, const int* in_sizes, int n_in,
                              void* d_out, int out_size, void* d_ws, size_t ws_size,
                              hipStream_t stream) {
  (void)in_sizes; (void)n_in; (void)out_size; (void)ws_size;
  const float* x     = (const float*)d_in[0];
  const float* wf    = (const float*)d_in[1];
  const float* wg    = (const float*)d_in[2];
  const float* wh    = (const float*)d_in[3];
  const float* wo    = (const float*)d_in[4];
  const float* gamma = (const float*)d_in[5];
  float* out = (float*)d_out;

  unsigned short* ws = (unsigned short*)d_ws;
  unsigned short* oB    = ws;               // [32768][256] bf16
  unsigned short* gB    = ws + 8388608;     // [32768][64]
  unsigned short* fB    = ws + 10485760;    // [8192][64]
  unsigned short* hT    = ws + 11010048;    // [8][256][1024]
  unsigned short* wcatT = ws + 13107200;    // [384][512]
  unsigned short* woT   = ws + 13303808;    // [512][256]

  pack_w<<<1280, dim3(256), 0, stream>>>(wf, wg, wh, wo, wcatT, woT);
  fgh_proj<<<512, dim3(512), 0, stream>>>(x, wcatT, fB, gB, hT);
  attn_mfma<<<256, dim3(512), 0, stream>>>((const __hip_bfloat16*)gB, (const __hip_bfloat16*)fB,
                                           (const __hip_bfloat16*)hT, oB);
  gemm_out_mfma<<<512, dim3(512), 0, stream>>>(oB, woT, x, gamma, out);
}